// Round 8
// baseline (1834.154 us; speedup 1.0000x reference)
//
#include <hip/hip_runtime.h>

// ---------------------------------------------------------------------------
// SequencePredictorRecurrentTransformer on MI355X (gfx950)
//
// I/O: fp32 (x int32). Internal: bf16 storage, fp32 accumulation.
// Layout [b][t][d] bt-major. Batch groups of Bg sized to ws_size.
//
// Round-8: attention loaders vectorized (uint4 global loads; 16B LDS stores
// for row-major arrays; rotation-swizzled scalar stores u=s^(lane&7) for the
// transposed Kt/Vt arrays -- kills the 8-way stride-72 write conflicts).
// PE table precomputed once (1 MB) instead of per-element transcendentals.
// GEMMs unchanged from round 7 (known-good VGPR-88/96 config).
// ---------------------------------------------------------------------------

typedef unsigned short u16;
typedef __bf16 bf16x8 __attribute__((ext_vector_type(8)));
typedef float f32x4 __attribute__((ext_vector_type(4)));

#define T_SEQ 2048
#define BATCH 32
#define NHEADS 8
#define CT 64
#define NCHUNK 32             // T/CT

__device__ __forceinline__ float b2f(u16 u) {
    union { unsigned int i; float f; } v; v.i = ((unsigned int)u) << 16; return v.f;
}
__device__ __forceinline__ u16 f2b(float f) {
    union { __bf16 b; u16 u; } v; v.b = (__bf16)f; return v.u;   // HW cvt, RNE
}

__device__ __forceinline__ void gl_lds16(const u16* g, u16* l) {
    __builtin_amdgcn_global_load_lds(
        (const __attribute__((address_space(1))) void*)g,
        (__attribute__((address_space(3))) void*)l,
        16, 0, 0);
}

// ---------------------------------------------------------------------------
// m97-structure GEMM (round-5 body): C[M,N] = act(A@BT^T + bias [+ R])
// BM=BN=128, BK=64, 4 waves x 64x64 acc. XOR-swizzled global_load_lds.
// ACT: 0=none, 1=relu, 2=phi(elu+1) where col < act_split.
// ---------------------------------------------------------------------------
template<int ACT, bool RES>
__global__ __launch_bounds__(256) void gemm_mx(
    const u16* __restrict__ A, const u16* __restrict__ BT,
    const float* __restrict__ bias, const u16* __restrict__ R,
    u16* __restrict__ C,
    int M, int N, int K, int act_split, int nbn, int GM)
{
    __shared__ __align__(16) u16 As[128 * 64];
    __shared__ __align__(16) u16 Bs[128 * 64];

    const int bid = blockIdx.x;
    const int gsz = GM * nbn;
    const int grp = bid / gsz, rm = bid % gsz;
    const int bm = (grp * GM + rm % GM) * 128;
    const int bn = (rm / GM) * 128;

    const int tid = threadIdx.x;
    const int lane = tid & 63;
    const int w = tid >> 6;
    const int lrow = lane & 15, quad = lane >> 4;
    const int wrow = (w >> 1) * 64, wcol = (w & 1) * 64;
    const int sr = lane >> 3;          // staging: row within 8-row chunk
    const int sg = lane & 7;           // staging: granule slot in row

    f32x4 acc[4][4] = {};

    for (int k0 = 0; k0 < K; k0 += 64) {
        #pragma unroll
        for (int ch4 = 0; ch4 < 4; ch4++) {
            const int chunk = w * 4 + ch4;        // 0..15 (8 rows each)
            const int r = chunk * 8 + sr;         // 0..127
            const int gs = sg ^ (r & 7);          // swizzled source granule
            gl_lds16(A  + (size_t)(bm + r) * K + k0 + gs * 8, As + chunk * 512);
            gl_lds16(BT + (size_t)(bn + r) * K + k0 + gs * 8, Bs + chunk * 512);
        }
        __syncthreads();
        #pragma unroll
        for (int half = 0; half < 2; half++) {
            bf16x8 af[4], bfv[4];
            #pragma unroll
            for (int i = 0; i < 4; i++) {
                const int r = wrow + i * 16 + lrow;
                const int gq = (half * 4 + quad) ^ (r & 7);
                af[i] = *(const bf16x8*)&As[r * 64 + gq * 8];
            }
            #pragma unroll
            for (int j = 0; j < 4; j++) {
                const int r = wcol + j * 16 + lrow;
                const int gq = (half * 4 + quad) ^ (r & 7);
                bfv[j] = *(const bf16x8*)&Bs[r * 64 + gq * 8];
            }
            #pragma unroll
            for (int i = 0; i < 4; i++)
                #pragma unroll
                for (int j = 0; j < 4; j++)
                    acc[i][j] = __builtin_amdgcn_mfma_f32_16x16x32_bf16(
                        af[i], bfv[j], acc[i][j], 0, 0, 0);
        }
        __syncthreads();
    }

    // Epilogue. D: col = lane&15, row = quad*4 + r.
    #pragma unroll
    for (int i = 0; i < 4; i++) {
        const int row0 = bm + wrow + i * 16 + quad * 4;
        #pragma unroll
        for (int j = 0; j < 4; j++) {
            const int col = bn + wcol + j * 16 + lrow;
            const float bb = bias[col];
            #pragma unroll
            for (int r = 0; r < 4; r++) {
                float v = acc[i][j][r] + bb;
                if (RES) v += b2f(R[(size_t)(row0 + r) * N + col]);
                if (ACT == 1) v = fmaxf(v, 0.f);
                if (ACT == 2) { if (col < act_split) v = (v > 0.f) ? (v + 1.f) : __expf(v); }
                C[(size_t)(row0 + r) * N + col] = f2b(v);
            }
        }
    }
}

// ---------------------------------------------------------------------------
// Small-N GEMM (final projection, N=64): fp32 out, swapped epilogue (16B st).
// ---------------------------------------------------------------------------
template<int BM, int BN, int WM, int WN>
__global__ __launch_bounds__(WM*WN*64) void gemm_sm(
    const u16* __restrict__ A, const u16* __restrict__ BT,
    const float* __restrict__ bias, float* __restrict__ C,
    int M, int N, int K)
{
    constexpr int BK = 32;
    constexpr int LDT = BK + 8;
    constexpr int NTHR = WM * WN * 64;
    __shared__ __align__(16) u16 As[BM * LDT];
    __shared__ __align__(16) u16 Bs[BN * LDT];

    const int tid = threadIdx.x;
    const int bm = blockIdx.y * BM;
    const int bn = blockIdx.x * BN;
    const int lane = tid & 63;
    const int wid = tid >> 6;
    const int wrow = (wid / WN) * (BM / WM);
    const int wcol = (wid % WN) * (BN / WN);
    constexpr int FM = BM / WM / 16;
    constexpr int FN = BN / WN / 16;
    const int lrow = lane & 15;
    const int lk = (lane >> 4) * 8;

    f32x4 acc[FM][FN] = {};

    for (int k0 = 0; k0 < K; k0 += BK) {
        #pragma unroll
        for (int g0 = 0; g0 < BM * 4; g0 += NTHR) {
            int g = g0 + tid;
            int row = g >> 2, kk = (g & 3) * 8;
            *(uint4*)&As[row * LDT + kk] =
                *(const uint4*)&A[(size_t)(bm + row) * K + k0 + kk];
        }
        #pragma unroll
        for (int g0 = 0; g0 < BN * 4; g0 += NTHR) {
            int g = g0 + tid;
            int row = g >> 2, kk = (g & 3) * 8;
            *(uint4*)&Bs[row * LDT + kk] =
                *(const uint4*)&BT[(size_t)(bn + row) * K + k0 + kk];
        }
        __syncthreads();
        bf16x8 af[FM], bfv[FN];
        #pragma unroll
        for (int i = 0; i < FM; i++)
            af[i] = *(const bf16x8*)&As[(wrow + i * 16 + lrow) * LDT + lk];
        #pragma unroll
        for (int j = 0; j < FN; j++)
            bfv[j] = *(const bf16x8*)&Bs[(wcol + j * 16 + lrow) * LDT + lk];
        #pragma unroll
        for (int i = 0; i < FM; i++)
            #pragma unroll
            for (int j = 0; j < FN; j++)
                acc[i][j] = __builtin_amdgcn_mfma_f32_16x16x32_bf16(
                    bfv[j], af[i], acc[i][j], 0, 0, 0);   // swapped
        __syncthreads();
    }

    #pragma unroll
    for (int i = 0; i < FM; i++) {
        const int row = bm + wrow + i * 16 + lrow;
        #pragma unroll
        for (int j = 0; j < FN; j++) {
            const int col0 = bn + wcol + j * 16 + (lane >> 4) * 4;
            const float4 bb = *(const float4*)&bias[col0];
            float4 o = { acc[i][j][0] + bb.x, acc[i][j][1] + bb.y,
                         acc[i][j][2] + bb.z, acc[i][j][3] + bb.w };
            *(float4*)&C[(size_t)row * N + col0] = o;
        }
    }
}

// ---------------------------------------------------------------------------
__global__ __launch_bounds__(256) void transpose_w(
    const float* __restrict__ src, u16* __restrict__ dst, int K, int N)
{
    __shared__ float tile[32][33];
    int bx = blockIdx.x, by = blockIdx.y;
    int tx = threadIdx.x & 31, ty = threadIdx.x >> 5;
    #pragma unroll
    for (int yy = 0; yy < 4; yy++) {
        int k = by * 32 + ty + yy * 8;
        tile[ty + yy * 8][tx] = src[(size_t)k * N + bx * 32 + tx];
    }
    __syncthreads();
    #pragma unroll
    for (int yy = 0; yy < 4; yy++) {
        int n = bx * 32 + ty + yy * 8;
        dst[(size_t)n * K + by * 32 + tx] = f2b(tile[tx][ty + yy * 8]);
    }
}

__global__ __launch_bounds__(256) void concat_bias(
    const float* __restrict__ bq, const float* __restrict__ bk,
    const float* __restrict__ bv, float* __restrict__ dst)
{
    int id = blockIdx.x * 256 + threadIdx.x;
    if (id >= 3072) return;
    int l = id / 1536, i = id % 1536;
    float v = (i < 512) ? bq[l * 512 + i]
            : (i < 1024) ? bk[l * 512 + i - 512]
                         : bv[l * 512 + i - 1024];
    dst[id] = v;
}

// ---------------------------------------------------------------------------
// PE table: pe[t][j] for t<2048, j<256 (bf16), computed once.
// ---------------------------------------------------------------------------
__global__ __launch_bounds__(256) void pe_table(u16* __restrict__ pe)
{
    int id = blockIdx.x * 256 + threadIdx.x;   // < 2048*256
    int t = id >> 8, j = id & 255;
    int i = j >> 1;
    float div = expf(-(float)(2 * i) * (9.210340371976184f / 256.f)); // ln(1e4)/256
    float arg = (float)t * div;
    pe[id] = f2b((j & 1) ? cosf(arg) : sinf(arg));
}

// ---------------------------------------------------------------------------
// Embedding (bt-major): pure gather from E and the PE table.
// ---------------------------------------------------------------------------
__global__ __launch_bounds__(256) void embed_kernel(
    const int* __restrict__ x, const float* __restrict__ E,
    const u16* __restrict__ pe, u16* __restrict__ h, int b0)
{
    int e = blockIdx.x * 256 + threadIdx.x;
    int r = e >> 9;
    int c = e & 511;
    int t = r & (T_SEQ - 1);
    int b = b0 + (r >> 11);
    u16 o;
    if (c < 256) o = f2b(E[x[t * BATCH + b] * 256 + c]);
    else         o = pe[t * 256 + (c - 256)];
    h[e] = o;
}

// ---------------------------------------------------------------------------
// Phase A (MFMA): S'_c[m][d] = sum_t V[t][m]*K[t][d] -> bf16; Z_c[d]=sum K.
// Loader: uint4 global loads; rotation-swizzled transpose writes (u=s^lane7).
// ---------------------------------------------------------------------------
__global__ __launch_bounds__(256) void attn_chunk_sums(
    const u16* __restrict__ qkv, u16* __restrict__ S, float* __restrict__ Z,
    int BHg)
{
    __shared__ __align__(16) u16 Kt[64 * 72], Vt[64 * 72];   // [d][t], [m][t]
    int bid = blockIdx.x;
    int bh = bid % BHg, c = bid / BHg;
    int bl = bh >> 3, hh = bh & 7;
    {
        const int m = threadIdx.x & 7;
        const int d0 = m * 8;
        #pragma unroll
        for (int pass = 0; pass < 2; pass++) {
            const int t = pass * 32 + (threadIdx.x >> 3);
            size_t rr = ((size_t)(bl * T_SEQ + c * 64 + t)) * 1536 + hh * 64 + d0;
            uint4 kv = *(const uint4*)&qkv[rr + 512];
            uint4 vv = *(const uint4*)&qkv[rr + 1024];
            const u16* kp = (const u16*)&kv;
            const u16* vp = (const u16*)&vv;
            #pragma unroll
            for (int s = 0; s < 8; s++) {
                int u = s ^ m;                        // rotation: spreads banks
                Kt[(d0 + u) * 72 + t] = kp[u];
                Vt[(d0 + u) * 72 + t] = vp[u];
            }
        }
    }
    __syncthreads();
    int lane = threadIdx.x & 63;
    int w = threadIdx.x >> 6;
    int lrow = lane & 15, quad = lane >> 4;
    int m0 = w * 16;
    f32x4 acc[4] = {};
    #pragma unroll
    for (int k0 = 0; k0 < 64; k0 += 32) {
        bf16x8 af = *(const bf16x8*)&Vt[(m0 + lrow) * 72 + k0 + quad * 8];
        #pragma unroll
        for (int jt = 0; jt < 4; jt++) {
            bf16x8 bf = *(const bf16x8*)&Kt[(jt * 16 + lrow) * 72 + k0 + quad * 8];
            acc[jt] = __builtin_amdgcn_mfma_f32_16x16x32_bf16(bf, af, acc[jt], 0, 0, 0);
        }
    }
    size_t base = ((size_t)c * BHg + bh) * 4096;
    const int m = m0 + lrow;
    #pragma unroll
    for (int jt = 0; jt < 4; jt++) {
        const int d0 = jt * 16 + quad * 4;
        union { u16 q[4]; uint2 u; } pk;
        #pragma unroll
        for (int r = 0; r < 4; r++) pk.q[r] = f2b(acc[jt][r]);
        *(uint2*)&S[base + m * 64 + d0] = pk.u;
    }
    if (threadIdx.x < 64) {
        float z = 0.f;
        #pragma unroll
        for (int t8 = 0; t8 < 64; t8 += 8) {
            bf16x8 kk = *(const bf16x8*)&Kt[threadIdx.x * 72 + t8];
            #pragma unroll
            for (int u = 0; u < 8; u++) z += (float)kk[u];
        }
        Z[((size_t)c * BHg + bh) * 64 + threadIdx.x] = z;
    }
}

// ---------------------------------------------------------------------------
// Phase B: exclusive prefix over chunks; register scan, loads all in flight.
// ---------------------------------------------------------------------------
__global__ __launch_bounds__(256) void attn_prefix(
    u16* __restrict__ S, float* __restrict__ Z, int BHg)
{
    int gid = blockIdx.x * 256 + threadIdx.x;   // < BHg*4096
    int bh = gid >> 12, e = gid & 4095;
    size_t stride = (size_t)BHg * 4096;
    size_t base = (size_t)bh * 4096 + e;
    float v[NCHUNK];
    #pragma unroll
    for (int c = 0; c < NCHUNK; c++) v[c] = b2f(S[base + c * stride]);
    float run = 0.f;
    #pragma unroll
    for (int c = 0; c < NCHUNK; c++) {
        float t = v[c]; S[base + c * stride] = f2b(run); run += t;
    }
    if (gid < BHg * 64) {
        size_t zb = (size_t)gid;
        size_t zs = (size_t)BHg * 64;
        float zv[NCHUNK];
        #pragma unroll
        for (int c = 0; c < NCHUNK; c++) zv[c] = Z[zb + c * zs];
        float zr = 0.f;
        #pragma unroll
        for (int c = 0; c < NCHUNK; c++) {
            float t = zv[c]; Z[zb + c * zs] = zr; zr += t;
        }
    }
}

// ---------------------------------------------------------------------------
// Phase C (MFMA): P=QK^T masked; O=(P@V + Q@S')/den.
// Loader: uint4 for Qs/Ks/Ssh; rotation-swizzled transpose for Vt.
// ---------------------------------------------------------------------------
__global__ __launch_bounds__(256) void attn_intra(
    const u16* __restrict__ qkv, const u16* __restrict__ Sp,
    const float* __restrict__ Zp, u16* __restrict__ out, int BHg)
{
    __shared__ __align__(16) u16 Qs[64 * 72], Ks[64 * 72], Vt[64 * 72],
                                 Ps[64 * 72], Ssh[64 * 72];
    __shared__ float Zsh[64], den2sh[64], den1sh[64];
    int bid = blockIdx.x;
    int bh = bid % BHg, c = bid / BHg;
    int bl = bh >> 3, hh = bh & 7;
    size_t sbase = ((size_t)c * BHg + bh) * 4096;
    {
        const int m = threadIdx.x & 7;
        const int d0 = m * 8;
        #pragma unroll
        for (int pass = 0; pass < 2; pass++) {
            const int t = pass * 32 + (threadIdx.x >> 3);
            size_t rr = ((size_t)(bl * T_SEQ + c * 64 + t)) * 1536 + hh * 64 + d0;
            *(uint4*)&Qs[t * 72 + d0] = *(const uint4*)&qkv[rr];
            *(uint4*)&Ks[t * 72 + d0] = *(const uint4*)&qkv[rr + 512];
            *(uint4*)&Ssh[t * 72 + d0] = *(const uint4*)&Sp[sbase + t * 64 + d0];
            uint4 vv = *(const uint4*)&qkv[rr + 1024];
            const u16* vp = (const u16*)&vv;
            #pragma unroll
            for (int s = 0; s < 8; s++) {
                int u = s ^ m;
                Vt[(d0 + u) * 72 + t] = vp[u];
            }
        }
    }
    if (threadIdx.x < 64)
        Zsh[threadIdx.x] = Zp[((size_t)c * BHg + bh) * 64 + threadIdx.x];
    __syncthreads();

    if (threadIdx.x < 64) {
        float s = 0.f;
        #pragma unroll
        for (int d8 = 0; d8 < 64; d8 += 8) {
            bf16x8 qq = *(const bf16x8*)&Qs[threadIdx.x * 72 + d8];
            #pragma unroll
            for (int u = 0; u < 8; u++) s += (float)qq[u] * Zsh[d8 + u];
        }
        den2sh[threadIdx.x] = s;
    }

    int lane = threadIdx.x & 63;
    int w = threadIdx.x >> 6;
    int lrow = lane & 15, quad = lane >> 4;
    int i0 = w * 16;

    // P = Q @ K^T (row = i via reg)
    f32x4 accp[4] = {};
    #pragma unroll
    for (int k0 = 0; k0 < 64; k0 += 32) {
        bf16x8 af = *(const bf16x8*)&Qs[(i0 + lrow) * 72 + k0 + quad * 8];
        #pragma unroll
        for (int jt = 0; jt < 4; jt++) {
            bf16x8 bf = *(const bf16x8*)&Ks[(jt * 16 + lrow) * 72 + k0 + quad * 8];
            accp[jt] = __builtin_amdgcn_mfma_f32_16x16x32_bf16(af, bf, accp[jt], 0, 0, 0);
        }
    }
    #pragma unroll
    for (int r = 0; r < 4; r++) {
        int row = i0 + quad * 4 + r;
        float d1 = 0.f;
        #pragma unroll
        for (int jt = 0; jt < 4; jt++) {
            int col = jt * 16 + lrow;
            float pv = (col <= row) ? accp[jt][r] : 0.f;
            d1 += pv;
            Ps[row * 72 + col] = f2b(pv);
        }
        #pragma unroll
        for (int off = 1; off < 16; off <<= 1)
            d1 += __shfl_xor(d1, off, 64);
        if (lrow == 0) den1sh[row] = d1;
    }
    __syncthreads();

    // O = Ps @ V + Q @ S'  (swapped: first operand = m side)
    f32x4 acco[4] = {};
    #pragma unroll
    for (int k0 = 0; k0 < 64; k0 += 32) {
        bf16x8 ps = *(const bf16x8*)&Ps[(i0 + lrow) * 72 + k0 + quad * 8];
        #pragma unroll
        for (int jt = 0; jt < 4; jt++) {
            bf16x8 vf = *(const bf16x8*)&Vt[(jt * 16 + lrow) * 72 + k0 + quad * 8];
            acco[jt] = __builtin_amdgcn_mfma_f32_16x16x32_bf16(vf, ps, acco[jt], 0, 0, 0);
        }
    }
    #pragma unroll
    for (int k0 = 0; k0 < 64; k0 += 32) {
        bf16x8 qf = *(const bf16x8*)&Qs[(i0 + lrow) * 72 + k0 + quad * 8];
        #pragma unroll
        for (int jt = 0; jt < 4; jt++) {
            bf16x8 sf = *(const bf16x8*)&Ssh[(jt * 16 + lrow) * 72 + k0 + quad * 8];
            acco[jt] = __builtin_amdgcn_mfma_f32_16x16x32_bf16(sf, qf, acco[jt], 0, 0, 0);
        }
    }
    const int i = i0 + lrow;
    const float inv = 1.f / (den1sh[i] + den2sh[i] + 1e-6f);
    size_t orow = ((size_t)(bl * T_SEQ + c * 64 + i)) * 512 + hh * 64;
    #pragma unroll
    for (int jt = 0; jt < 4; jt++) {
        const int m0 = jt * 16 + quad * 4;
        union { u16 q[4]; uint2 u; } pk;
        #pragma unroll
        for (int r = 0; r < 4; r++) pk.q[r] = f2b(acco[jt][r] * inv);
        *(uint2*)&out[orow + m0] = pk.u;
    }
}

// ---------------------------------------------------------------------------
// LayerNorm (single input stream; residual pre-added in GEMM epilogue).
// ---------------------------------------------------------------------------
__global__ __launch_bounds__(256) void ln_kernel(
    const u16* __restrict__ s_in,
    const float* __restrict__ g, const float* __restrict__ be, u16* __restrict__ out)
{
    int row = blockIdx.x * 4 + (threadIdx.x >> 6);
    int lane = threadIdx.x & 63;
    size_t base = (size_t)row * 512 + lane * 8;
    uint4 hv = *(const uint4*)&s_in[base];
    const u16* hp = (const u16*)&hv;
    float x[8]; float s = 0.f;
    #pragma unroll
    for (int i = 0; i < 8; i++) { x[i] = b2f(hp[i]); s += x[i]; }
    #pragma unroll
    for (int off = 32; off > 0; off >>= 1) s += __shfl_xor(s, off, 64);
    float m = s * (1.f / 512.f);
    float vs = 0.f;
    #pragma unroll
    for (int i = 0; i < 8; i++) { float t = x[i] - m; vs += t * t; }
    #pragma unroll
    for (int off = 32; off > 0; off >>= 1) vs += __shfl_xor(vs, off, 64);
    float rstd = rsqrtf(vs * (1.f / 512.f) + 1e-5f);
    union { u16 u[8]; uint4 v; } o;
    #pragma unroll
    for (int i = 0; i < 8; i++)
        o.u[i] = f2b((x[i] - m) * rstd * g[lane * 8 + i] + be[lane * 8 + i]);
    *(uint4*)&out[base] = o.v;
}

// ---------------------------------------------------------------------------
extern "C" void kernel_launch(void* const* d_in, const int* in_sizes, int n_in,
                              void* d_out, int out_size, void* d_ws, size_t ws_size,
                              hipStream_t stream)
{
    const int*   x  = (const int*)d_in[0];
    const float* E  = (const float*)d_in[1];
    const float* Wq = (const float*)d_in[2];
    const float* bq = (const float*)d_in[3];
    const float* Wk = (const float*)d_in[4];
    const float* bk = (const float*)d_in[5];
    const float* Wv = (const float*)d_in[6];
    const float* bv = (const float*)d_in[7];
    const float* Wo = (const float*)d_in[8];
    const float* bo = (const float*)d_in[9];
    const float* g1 = (const float*)d_in[10];
    const float* be1= (const float*)d_in[11];
    const float* W1 = (const float*)d_in[12];
    const float* b1 = (const float*)d_in[13];
    const float* W2 = (const float*)d_in[14];
    const float* b2 = (const float*)d_in[15];
    const float* g2 = (const float*)d_in[16];
    const float* be2= (const float*)d_in[17];
    const float* Wp = (const float*)d_in[18];
    const float* bp = (const float*)d_in[19];

    // --- fixed region: bf16 transposed weights + PE table + fp32 qkv bias ---
    char* p = (char*)d_ws;
    u16* qkvT = (u16*)p; p += (size_t)2 * 1536 * 512 * 2;
    u16* woT  = (u16*)p; p += (size_t)2 * 512 * 512 * 2;
    u16* w1T  = (u16*)p; p += (size_t)2 * 2048 * 512 * 2;
    u16* w2T  = (u16*)p; p += (size_t)2 * 512 * 2048 * 2;
    u16* wpT  = (u16*)p; p += (size_t)64 * 512 * 2;
    u16* pe   = (u16*)p; p += (size_t)T_SEQ * 256 * 2;     // 1 MiB
    float* bqkv = (float*)p; p += (size_t)16384;
    size_t fixed = (size_t)(p - (char*)d_ws);

    // --- adaptive batch group: Bg * 12.65 MiB ---
    const size_t perB = 12648448ULL;
    int Bg = 32;
    while (Bg > 1 && fixed + (size_t)Bg * perB > ws_size) Bg >>= 1;
    const int rows = Bg * T_SEQ;
    const int BHg = Bg * NHEADS;
    const int nbm = rows / 128;

    u16* h      = (u16*)p; p += (size_t)rows * 512 * 2;
    u16* qkvBig = (u16*)p; p += (size_t)rows * 2048 * 2;
    u16* am     = (u16*)p; p += (size_t)rows * 512 * 2;
    float* Z    = (float*)p; p += (size_t)BHg * NCHUNK * 64 * 4;
    u16* qkv = qkvBig;                        // rows x 1536 during attention
    u16* Sb  = qkvBig + (size_t)rows * 1536;  // bf16 S' tail
    u16* ff1 = qkvBig;                        // rows x 2048 during FF
    u16* o_  = qkvBig;                        // rows x 512 Wo output (h+attn)

    dim3 blk(256);

    for (int l = 0; l < 2; l++) {
        transpose_w<<<dim3(16, 16), blk, 0, stream>>>(Wq + (size_t)l * 262144, qkvT + (size_t)l * 786432,          512, 512);
        transpose_w<<<dim3(16, 16), blk, 0, stream>>>(Wk + (size_t)l * 262144, qkvT + (size_t)l * 786432 + 262144, 512, 512);
        transpose_w<<<dim3(16, 16), blk, 0, stream>>>(Wv + (size_t)l * 262144, qkvT + (size_t)l * 786432 + 524288, 512, 512);
        transpose_w<<<dim3(16, 16), blk, 0, stream>>>(Wo + (size_t)l * 262144, woT + (size_t)l * 262144,           512, 512);
        transpose_w<<<dim3(64, 16), blk, 0, stream>>>(W1 + (size_t)l * 1048576, w1T + (size_t)l * 1048576,         512, 2048);
        transpose_w<<<dim3(16, 64), blk, 0, stream>>>(W2 + (size_t)l * 1048576, w2T + (size_t)l * 1048576,         2048, 512);
    }
    transpose_w<<<dim3(2, 16), blk, 0, stream>>>(Wp, wpT, 512, 64);
    concat_bias<<<12, blk, 0, stream>>>(bq, bk, bv, bqkv);
    pe_table<<<T_SEQ, blk, 0, stream>>>(pe);

    for (int b0 = 0; b0 < BATCH; b0 += Bg) {
        embed_kernel<<<rows * 2, blk, 0, stream>>>(x, E, pe, h, b0);

        for (int l = 0; l < 2; l++) {
            gemm_mx<2, false><<<dim3(nbm * 12), blk, 0, stream>>>(
                h, qkvT + (size_t)l * 786432, bqkv + l * 1536, nullptr, qkv,
                rows, 1536, 512, 1024, 12, 8);
            attn_chunk_sums<<<NCHUNK * BHg, blk, 0, stream>>>(qkv, Sb, Z, BHg);
            attn_prefix<<<BHg * 16, blk, 0, stream>>>(Sb, Z, BHg);
            attn_intra<<<NCHUNK * BHg, blk, 0, stream>>>(qkv, Sb, Z, am, BHg);
            gemm_mx<0, true><<<dim3(nbm * 4), blk, 0, stream>>>(
                am, woT + (size_t)l * 262144, bo + l * 512, h, o_,
                rows, 512, 512, 0, 4, 8);
            ln_kernel<<<rows / 4, blk, 0, stream>>>(o_, g1 + l * 512, be1 + l * 512, h);
            gemm_mx<1, false><<<dim3(nbm * 16), blk, 0, stream>>>(
                h, w1T + (size_t)l * 1048576, b1 + l * 2048, nullptr, ff1,
                rows, 2048, 512, 0, 16, 8);
            gemm_mx<0, true><<<dim3(nbm * 4), blk, 0, stream>>>(
                ff1, w2T + (size_t)l * 1048576, b2 + l * 512, h, am,
                rows, 512, 2048, 0, 4, 8);
            ln_kernel<<<rows / 4, blk, 0, stream>>>(am, g2 + l * 512, be2 + l * 512, h);
        }

        gemm_sm<64, 64, 2, 2><<<dim3(1, rows / 64), blk, 0, stream>>>(
            h, wpT, bp, (float*)d_out + (size_t)b0 * T_SEQ * 64, rows, 64, 512);
    }

    (void)in_sizes; (void)n_in; (void)out_size; (void)ws_size;
}

// Round 9
// 1695.289 us; speedup vs baseline: 1.0819x; 1.0819x over previous
//
#include <hip/hip_runtime.h>

// ---------------------------------------------------------------------------
// SequencePredictorRecurrentTransformer on MI355X (gfx950)
//
// I/O: fp32 (x int32). Internal: bf16 storage, fp32 accumulation.
// Layout [b][t][d] bt-major. Batch groups of Bg sized to ws_size.
//
// Round-9: revert round-8's attention loaders (the u=s^m rotation indexed
// registers DYNAMICALLY -> cndmask/scratch chains, -7%). Back to round-7
// scalar loaders (known-good 1709us). Keep: PE table precompute + gather
// embed. GEMMs unchanged (round-5 body, VGPR 88/96, XOR-swizzled DMA).
// ---------------------------------------------------------------------------

typedef unsigned short u16;
typedef __bf16 bf16x8 __attribute__((ext_vector_type(8)));
typedef float f32x4 __attribute__((ext_vector_type(4)));

#define T_SEQ 2048
#define BATCH 32
#define NHEADS 8
#define CT 64
#define NCHUNK 32             // T/CT

__device__ __forceinline__ float b2f(u16 u) {
    union { unsigned int i; float f; } v; v.i = ((unsigned int)u) << 16; return v.f;
}
__device__ __forceinline__ u16 f2b(float f) {
    union { __bf16 b; u16 u; } v; v.b = (__bf16)f; return v.u;   // HW cvt, RNE
}

__device__ __forceinline__ void gl_lds16(const u16* g, u16* l) {
    __builtin_amdgcn_global_load_lds(
        (const __attribute__((address_space(1))) void*)g,
        (__attribute__((address_space(3))) void*)l,
        16, 0, 0);
}

// ---------------------------------------------------------------------------
// m97-structure GEMM (round-5 body): C[M,N] = act(A@BT^T + bias [+ R])
// BM=BN=128, BK=64, 4 waves x 64x64 acc. XOR-swizzled global_load_lds.
// ACT: 0=none, 1=relu, 2=phi(elu+1) where col < act_split.
// ---------------------------------------------------------------------------
template<int ACT, bool RES>
__global__ __launch_bounds__(256) void gemm_mx(
    const u16* __restrict__ A, const u16* __restrict__ BT,
    const float* __restrict__ bias, const u16* __restrict__ R,
    u16* __restrict__ C,
    int M, int N, int K, int act_split, int nbn, int GM)
{
    __shared__ __align__(16) u16 As[128 * 64];
    __shared__ __align__(16) u16 Bs[128 * 64];

    const int bid = blockIdx.x;
    const int gsz = GM * nbn;
    const int grp = bid / gsz, rm = bid % gsz;
    const int bm = (grp * GM + rm % GM) * 128;
    const int bn = (rm / GM) * 128;

    const int tid = threadIdx.x;
    const int lane = tid & 63;
    const int w = tid >> 6;
    const int lrow = lane & 15, quad = lane >> 4;
    const int wrow = (w >> 1) * 64, wcol = (w & 1) * 64;
    const int sr = lane >> 3;          // staging: row within 8-row chunk
    const int sg = lane & 7;           // staging: granule slot in row

    f32x4 acc[4][4] = {};

    for (int k0 = 0; k0 < K; k0 += 64) {
        #pragma unroll
        for (int ch4 = 0; ch4 < 4; ch4++) {
            const int chunk = w * 4 + ch4;        // 0..15 (8 rows each)
            const int r = chunk * 8 + sr;         // 0..127
            const int gs = sg ^ (r & 7);          // swizzled source granule
            gl_lds16(A  + (size_t)(bm + r) * K + k0 + gs * 8, As + chunk * 512);
            gl_lds16(BT + (size_t)(bn + r) * K + k0 + gs * 8, Bs + chunk * 512);
        }
        __syncthreads();
        #pragma unroll
        for (int half = 0; half < 2; half++) {
            bf16x8 af[4], bfv[4];
            #pragma unroll
            for (int i = 0; i < 4; i++) {
                const int r = wrow + i * 16 + lrow;
                const int gq = (half * 4 + quad) ^ (r & 7);
                af[i] = *(const bf16x8*)&As[r * 64 + gq * 8];
            }
            #pragma unroll
            for (int j = 0; j < 4; j++) {
                const int r = wcol + j * 16 + lrow;
                const int gq = (half * 4 + quad) ^ (r & 7);
                bfv[j] = *(const bf16x8*)&Bs[r * 64 + gq * 8];
            }
            #pragma unroll
            for (int i = 0; i < 4; i++)
                #pragma unroll
                for (int j = 0; j < 4; j++)
                    acc[i][j] = __builtin_amdgcn_mfma_f32_16x16x32_bf16(
                        af[i], bfv[j], acc[i][j], 0, 0, 0);
        }
        __syncthreads();
    }

    // Epilogue. D: col = lane&15, row = quad*4 + r.
    #pragma unroll
    for (int i = 0; i < 4; i++) {
        const int row0 = bm + wrow + i * 16 + quad * 4;
        #pragma unroll
        for (int j = 0; j < 4; j++) {
            const int col = bn + wcol + j * 16 + lrow;
            const float bb = bias[col];
            #pragma unroll
            for (int r = 0; r < 4; r++) {
                float v = acc[i][j][r] + bb;
                if (RES) v += b2f(R[(size_t)(row0 + r) * N + col]);
                if (ACT == 1) v = fmaxf(v, 0.f);
                if (ACT == 2) { if (col < act_split) v = (v > 0.f) ? (v + 1.f) : __expf(v); }
                C[(size_t)(row0 + r) * N + col] = f2b(v);
            }
        }
    }
}

// ---------------------------------------------------------------------------
// Small-N GEMM (final projection, N=64): fp32 out, swapped epilogue (16B st).
// ---------------------------------------------------------------------------
template<int BM, int BN, int WM, int WN>
__global__ __launch_bounds__(WM*WN*64) void gemm_sm(
    const u16* __restrict__ A, const u16* __restrict__ BT,
    const float* __restrict__ bias, float* __restrict__ C,
    int M, int N, int K)
{
    constexpr int BK = 32;
    constexpr int LDT = BK + 8;
    constexpr int NTHR = WM * WN * 64;
    __shared__ __align__(16) u16 As[BM * LDT];
    __shared__ __align__(16) u16 Bs[BN * LDT];

    const int tid = threadIdx.x;
    const int bm = blockIdx.y * BM;
    const int bn = blockIdx.x * BN;
    const int lane = tid & 63;
    const int wid = tid >> 6;
    const int wrow = (wid / WN) * (BM / WM);
    const int wcol = (wid % WN) * (BN / WN);
    constexpr int FM = BM / WM / 16;
    constexpr int FN = BN / WN / 16;
    const int lrow = lane & 15;
    const int lk = (lane >> 4) * 8;

    f32x4 acc[FM][FN] = {};

    for (int k0 = 0; k0 < K; k0 += BK) {
        #pragma unroll
        for (int g0 = 0; g0 < BM * 4; g0 += NTHR) {
            int g = g0 + tid;
            int row = g >> 2, kk = (g & 3) * 8;
            *(uint4*)&As[row * LDT + kk] =
                *(const uint4*)&A[(size_t)(bm + row) * K + k0 + kk];
        }
        #pragma unroll
        for (int g0 = 0; g0 < BN * 4; g0 += NTHR) {
            int g = g0 + tid;
            int row = g >> 2, kk = (g & 3) * 8;
            *(uint4*)&Bs[row * LDT + kk] =
                *(const uint4*)&BT[(size_t)(bn + row) * K + k0 + kk];
        }
        __syncthreads();
        bf16x8 af[FM], bfv[FN];
        #pragma unroll
        for (int i = 0; i < FM; i++)
            af[i] = *(const bf16x8*)&As[(wrow + i * 16 + lrow) * LDT + lk];
        #pragma unroll
        for (int j = 0; j < FN; j++)
            bfv[j] = *(const bf16x8*)&Bs[(wcol + j * 16 + lrow) * LDT + lk];
        #pragma unroll
        for (int i = 0; i < FM; i++)
            #pragma unroll
            for (int j = 0; j < FN; j++)
                acc[i][j] = __builtin_amdgcn_mfma_f32_16x16x32_bf16(
                    bfv[j], af[i], acc[i][j], 0, 0, 0);   // swapped
        __syncthreads();
    }

    #pragma unroll
    for (int i = 0; i < FM; i++) {
        const int row = bm + wrow + i * 16 + lrow;
        #pragma unroll
        for (int j = 0; j < FN; j++) {
            const int col0 = bn + wcol + j * 16 + (lane >> 4) * 4;
            const float4 bb = *(const float4*)&bias[col0];
            float4 o = { acc[i][j][0] + bb.x, acc[i][j][1] + bb.y,
                         acc[i][j][2] + bb.z, acc[i][j][3] + bb.w };
            *(float4*)&C[(size_t)row * N + col0] = o;
        }
    }
}

// ---------------------------------------------------------------------------
__global__ __launch_bounds__(256) void transpose_w(
    const float* __restrict__ src, u16* __restrict__ dst, int K, int N)
{
    __shared__ float tile[32][33];
    int bx = blockIdx.x, by = blockIdx.y;
    int tx = threadIdx.x & 31, ty = threadIdx.x >> 5;
    #pragma unroll
    for (int yy = 0; yy < 4; yy++) {
        int k = by * 32 + ty + yy * 8;
        tile[ty + yy * 8][tx] = src[(size_t)k * N + bx * 32 + tx];
    }
    __syncthreads();
    #pragma unroll
    for (int yy = 0; yy < 4; yy++) {
        int n = bx * 32 + ty + yy * 8;
        dst[(size_t)n * K + by * 32 + tx] = f2b(tile[tx][ty + yy * 8]);
    }
}

__global__ __launch_bounds__(256) void concat_bias(
    const float* __restrict__ bq, const float* __restrict__ bk,
    const float* __restrict__ bv, float* __restrict__ dst)
{
    int id = blockIdx.x * 256 + threadIdx.x;
    if (id >= 3072) return;
    int l = id / 1536, i = id % 1536;
    float v = (i < 512) ? bq[l * 512 + i]
            : (i < 1024) ? bk[l * 512 + i - 512]
                         : bv[l * 512 + i - 1024];
    dst[id] = v;
}

// ---------------------------------------------------------------------------
// PE table: pe[t][j] for t<2048, j<256 (bf16), computed once.
// ---------------------------------------------------------------------------
__global__ __launch_bounds__(256) void pe_table(u16* __restrict__ pe)
{
    int id = blockIdx.x * 256 + threadIdx.x;   // < 2048*256
    int t = id >> 8, j = id & 255;
    int i = j >> 1;
    float div = expf(-(float)(2 * i) * (9.210340371976184f / 256.f)); // ln(1e4)/256
    float arg = (float)t * div;
    pe[id] = f2b((j & 1) ? cosf(arg) : sinf(arg));
}

// ---------------------------------------------------------------------------
// Embedding (bt-major): pure gather from E and the PE table.
// ---------------------------------------------------------------------------
__global__ __launch_bounds__(256) void embed_kernel(
    const int* __restrict__ x, const float* __restrict__ E,
    const u16* __restrict__ pe, u16* __restrict__ h, int b0)
{
    int e = blockIdx.x * 256 + threadIdx.x;
    int r = e >> 9;
    int c = e & 511;
    int t = r & (T_SEQ - 1);
    int b = b0 + (r >> 11);
    u16 o;
    if (c < 256) o = f2b(E[x[t * BATCH + b] * 256 + c]);
    else         o = pe[t * 256 + (c - 256)];
    h[e] = o;
}

// ---------------------------------------------------------------------------
// Phase A (MFMA): S'_c[m][d] = sum_t V[t][m]*K[t][d] -> bf16; Z_c[d]=sum K.
// (round-7 loader: scalar transposed writes, static indexing)
// ---------------------------------------------------------------------------
__global__ __launch_bounds__(256) void attn_chunk_sums(
    const u16* __restrict__ qkv, u16* __restrict__ S, float* __restrict__ Z,
    int BHg)
{
    __shared__ __align__(16) u16 Kt[64 * 72], Vt[64 * 72];   // [d][t], [m][t]
    int bid = blockIdx.x;
    int bh = bid % BHg, c = bid / BHg;
    int bl = bh >> 3, hh = bh & 7;
    for (int idx = threadIdx.x; idx < 4096; idx += 256) {
        int t = idx >> 6, d = idx & 63;
        size_t r = ((size_t)(bl * T_SEQ + c * 64 + t)) * 1536 + hh * 64 + d;
        Kt[d * 72 + t] = qkv[r + 512];
        Vt[d * 72 + t] = qkv[r + 1024];
    }
    __syncthreads();
    int lane = threadIdx.x & 63;
    int w = threadIdx.x >> 6;
    int lrow = lane & 15, quad = lane >> 4;
    int m0 = w * 16;
    f32x4 acc[4] = {};
    #pragma unroll
    for (int k0 = 0; k0 < 64; k0 += 32) {
        bf16x8 af = *(const bf16x8*)&Vt[(m0 + lrow) * 72 + k0 + quad * 8];
        #pragma unroll
        for (int jt = 0; jt < 4; jt++) {
            bf16x8 bf = *(const bf16x8*)&Kt[(jt * 16 + lrow) * 72 + k0 + quad * 8];
            acc[jt] = __builtin_amdgcn_mfma_f32_16x16x32_bf16(bf, af, acc[jt], 0, 0, 0);
        }
    }
    size_t base = ((size_t)c * BHg + bh) * 4096;
    const int m = m0 + lrow;
    #pragma unroll
    for (int jt = 0; jt < 4; jt++) {
        const int d0 = jt * 16 + quad * 4;
        union { u16 q[4]; uint2 u; } pk;
        #pragma unroll
        for (int r = 0; r < 4; r++) pk.q[r] = f2b(acc[jt][r]);
        *(uint2*)&S[base + m * 64 + d0] = pk.u;
    }
    if (threadIdx.x < 64) {
        float z = 0.f;
        #pragma unroll
        for (int t8 = 0; t8 < 64; t8 += 8) {
            bf16x8 kk = *(const bf16x8*)&Kt[threadIdx.x * 72 + t8];
            #pragma unroll
            for (int u = 0; u < 8; u++) z += (float)kk[u];
        }
        Z[((size_t)c * BHg + bh) * 64 + threadIdx.x] = z;
    }
}

// ---------------------------------------------------------------------------
// Phase B: exclusive prefix over chunks; register scan, loads all in flight.
// ---------------------------------------------------------------------------
__global__ __launch_bounds__(256) void attn_prefix(
    u16* __restrict__ S, float* __restrict__ Z, int BHg)
{
    int gid = blockIdx.x * 256 + threadIdx.x;   // < BHg*4096
    int bh = gid >> 12, e = gid & 4095;
    size_t stride = (size_t)BHg * 4096;
    size_t base = (size_t)bh * 4096 + e;
    float v[NCHUNK];
    #pragma unroll
    for (int c = 0; c < NCHUNK; c++) v[c] = b2f(S[base + c * stride]);
    float run = 0.f;
    #pragma unroll
    for (int c = 0; c < NCHUNK; c++) {
        float t = v[c]; S[base + c * stride] = f2b(run); run += t;
    }
    if (gid < BHg * 64) {
        size_t zb = (size_t)gid;
        size_t zs = (size_t)BHg * 64;
        float zv[NCHUNK];
        #pragma unroll
        for (int c = 0; c < NCHUNK; c++) zv[c] = Z[zb + c * zs];
        float zr = 0.f;
        #pragma unroll
        for (int c = 0; c < NCHUNK; c++) {
            float t = zv[c]; Z[zb + c * zs] = zr; zr += t;
        }
    }
}

// ---------------------------------------------------------------------------
// Phase C (MFMA): P=QK^T masked; O=(P@V + Q@S')/den. (round-7 loader)
// ---------------------------------------------------------------------------
__global__ __launch_bounds__(256) void attn_intra(
    const u16* __restrict__ qkv, const u16* __restrict__ Sp,
    const float* __restrict__ Zp, u16* __restrict__ out, int BHg)
{
    __shared__ __align__(16) u16 Qs[64 * 72], Ks[64 * 72], Vt[64 * 72],
                                 Ps[64 * 72], Ssh[64 * 72];
    __shared__ float Zsh[64], den2sh[64], den1sh[64];
    int bid = blockIdx.x;
    int bh = bid % BHg, c = bid / BHg;
    int bl = bh >> 3, hh = bh & 7;
    size_t sbase = ((size_t)c * BHg + bh) * 4096;
    for (int idx = threadIdx.x; idx < 4096; idx += 256) {
        int t = idx >> 6, d = idx & 63;
        size_t r = ((size_t)(bl * T_SEQ + c * 64 + t)) * 1536 + hh * 64 + d;
        Qs[t * 72 + d] = qkv[r];
        Ks[t * 72 + d] = qkv[r + 512];
        Vt[d * 72 + t] = qkv[r + 1024];         // [m][t]
        Ssh[t * 72 + d] = Sp[sbase + idx];      // [m][d]
    }
    if (threadIdx.x < 64)
        Zsh[threadIdx.x] = Zp[((size_t)c * BHg + bh) * 64 + threadIdx.x];
    __syncthreads();

    if (threadIdx.x < 64) {
        float s = 0.f;
        #pragma unroll
        for (int d8 = 0; d8 < 64; d8 += 8) {
            bf16x8 qq = *(const bf16x8*)&Qs[threadIdx.x * 72 + d8];
            #pragma unroll
            for (int u = 0; u < 8; u++) s += (float)qq[u] * Zsh[d8 + u];
        }
        den2sh[threadIdx.x] = s;
    }

    int lane = threadIdx.x & 63;
    int w = threadIdx.x >> 6;
    int lrow = lane & 15, quad = lane >> 4;
    int i0 = w * 16;

    // P = Q @ K^T (row = i via reg)
    f32x4 accp[4] = {};
    #pragma unroll
    for (int k0 = 0; k0 < 64; k0 += 32) {
        bf16x8 af = *(const bf16x8*)&Qs[(i0 + lrow) * 72 + k0 + quad * 8];
        #pragma unroll
        for (int jt = 0; jt < 4; jt++) {
            bf16x8 bf = *(const bf16x8*)&Ks[(jt * 16 + lrow) * 72 + k0 + quad * 8];
            accp[jt] = __builtin_amdgcn_mfma_f32_16x16x32_bf16(af, bf, accp[jt], 0, 0, 0);
        }
    }
    #pragma unroll
    for (int r = 0; r < 4; r++) {
        int row = i0 + quad * 4 + r;
        float d1 = 0.f;
        #pragma unroll
        for (int jt = 0; jt < 4; jt++) {
            int col = jt * 16 + lrow;
            float pv = (col <= row) ? accp[jt][r] : 0.f;
            d1 += pv;
            Ps[row * 72 + col] = f2b(pv);
        }
        #pragma unroll
        for (int off = 1; off < 16; off <<= 1)
            d1 += __shfl_xor(d1, off, 64);
        if (lrow == 0) den1sh[row] = d1;
    }
    __syncthreads();

    // O = Ps @ V + Q @ S'  (swapped: first operand = m side)
    f32x4 acco[4] = {};
    #pragma unroll
    for (int k0 = 0; k0 < 64; k0 += 32) {
        bf16x8 ps = *(const bf16x8*)&Ps[(i0 + lrow) * 72 + k0 + quad * 8];
        #pragma unroll
        for (int jt = 0; jt < 4; jt++) {
            bf16x8 vf = *(const bf16x8*)&Vt[(jt * 16 + lrow) * 72 + k0 + quad * 8];
            acco[jt] = __builtin_amdgcn_mfma_f32_16x16x32_bf16(vf, ps, acco[jt], 0, 0, 0);
        }
    }
    #pragma unroll
    for (int k0 = 0; k0 < 64; k0 += 32) {
        bf16x8 qf = *(const bf16x8*)&Qs[(i0 + lrow) * 72 + k0 + quad * 8];
        #pragma unroll
        for (int jt = 0; jt < 4; jt++) {
            bf16x8 sf = *(const bf16x8*)&Ssh[(jt * 16 + lrow) * 72 + k0 + quad * 8];
            acco[jt] = __builtin_amdgcn_mfma_f32_16x16x32_bf16(sf, qf, acco[jt], 0, 0, 0);
        }
    }
    const int i = i0 + lrow;
    const float inv = 1.f / (den1sh[i] + den2sh[i] + 1e-6f);
    size_t orow = ((size_t)(bl * T_SEQ + c * 64 + i)) * 512 + hh * 64;
    #pragma unroll
    for (int jt = 0; jt < 4; jt++) {
        const int m0 = jt * 16 + quad * 4;
        union { u16 q[4]; uint2 u; } pk;
        #pragma unroll
        for (int r = 0; r < 4; r++) pk.q[r] = f2b(acco[jt][r] * inv);
        *(uint2*)&out[orow + m0] = pk.u;
    }
}

// ---------------------------------------------------------------------------
// LayerNorm (single input stream; residual pre-added in GEMM epilogue).
// ---------------------------------------------------------------------------
__global__ __launch_bounds__(256) void ln_kernel(
    const u16* __restrict__ s_in,
    const float* __restrict__ g, const float* __restrict__ be, u16* __restrict__ out)
{
    int row = blockIdx.x * 4 + (threadIdx.x >> 6);
    int lane = threadIdx.x & 63;
    size_t base = (size_t)row * 512 + lane * 8;
    uint4 hv = *(const uint4*)&s_in[base];
    const u16* hp = (const u16*)&hv;
    float x[8]; float s = 0.f;
    #pragma unroll
    for (int i = 0; i < 8; i++) { x[i] = b2f(hp[i]); s += x[i]; }
    #pragma unroll
    for (int off = 32; off > 0; off >>= 1) s += __shfl_xor(s, off, 64);
    float m = s * (1.f / 512.f);
    float vs = 0.f;
    #pragma unroll
    for (int i = 0; i < 8; i++) { float t = x[i] - m; vs += t * t; }
    #pragma unroll
    for (int off = 32; off > 0; off >>= 1) vs += __shfl_xor(vs, off, 64);
    float rstd = rsqrtf(vs * (1.f / 512.f) + 1e-5f);
    union { u16 u[8]; uint4 v; } o;
    #pragma unroll
    for (int i = 0; i < 8; i++)
        o.u[i] = f2b((x[i] - m) * rstd * g[lane * 8 + i] + be[lane * 8 + i]);
    *(uint4*)&out[base] = o.v;
}

// ---------------------------------------------------------------------------
extern "C" void kernel_launch(void* const* d_in, const int* in_sizes, int n_in,
                              void* d_out, int out_size, void* d_ws, size_t ws_size,
                              hipStream_t stream)
{
    const int*   x  = (const int*)d_in[0];
    const float* E  = (const float*)d_in[1];
    const float* Wq = (const float*)d_in[2];
    const float* bq = (const float*)d_in[3];
    const float* Wk = (const float*)d_in[4];
    const float* bk = (const float*)d_in[5];
    const float* Wv = (const float*)d_in[6];
    const float* bv = (const float*)d_in[7];
    const float* Wo = (const float*)d_in[8];
    const float* bo = (const float*)d_in[9];
    const float* g1 = (const float*)d_in[10];
    const float* be1= (const float*)d_in[11];
    const float* W1 = (const float*)d_in[12];
    const float* b1 = (const float*)d_in[13];
    const float* W2 = (const float*)d_in[14];
    const float* b2 = (const float*)d_in[15];
    const float* g2 = (const float*)d_in[16];
    const float* be2= (const float*)d_in[17];
    const float* Wp = (const float*)d_in[18];
    const float* bp = (const float*)d_in[19];

    // --- fixed region: bf16 transposed weights + PE table + fp32 qkv bias ---
    char* p = (char*)d_ws;
    u16* qkvT = (u16*)p; p += (size_t)2 * 1536 * 512 * 2;
    u16* woT  = (u16*)p; p += (size_t)2 * 512 * 512 * 2;
    u16* w1T  = (u16*)p; p += (size_t)2 * 2048 * 512 * 2;
    u16* w2T  = (u16*)p; p += (size_t)2 * 512 * 2048 * 2;
    u16* wpT  = (u16*)p; p += (size_t)64 * 512 * 2;
    u16* pe   = (u16*)p; p += (size_t)T_SEQ * 256 * 2;     // 1 MiB
    float* bqkv = (float*)p; p += (size_t)16384;
    size_t fixed = (size_t)(p - (char*)d_ws);

    // --- adaptive batch group: Bg * 12.65 MiB ---
    const size_t perB = 12648448ULL;
    int Bg = 32;
    while (Bg > 1 && fixed + (size_t)Bg * perB > ws_size) Bg >>= 1;
    const int rows = Bg * T_SEQ;
    const int BHg = Bg * NHEADS;
    const int nbm = rows / 128;

    u16* h      = (u16*)p; p += (size_t)rows * 512 * 2;
    u16* qkvBig = (u16*)p; p += (size_t)rows * 2048 * 2;
    u16* am     = (u16*)p; p += (size_t)rows * 512 * 2;
    float* Z    = (float*)p; p += (size_t)BHg * NCHUNK * 64 * 4;
    u16* qkv = qkvBig;                        // rows x 1536 during attention
    u16* Sb  = qkvBig + (size_t)rows * 1536;  // bf16 S' tail
    u16* ff1 = qkvBig;                        // rows x 2048 during FF
    u16* o_  = qkvBig;                        // rows x 512 Wo output (h+attn)

    dim3 blk(256);

    for (int l = 0; l < 2; l++) {
        transpose_w<<<dim3(16, 16), blk, 0, stream>>>(Wq + (size_t)l * 262144, qkvT + (size_t)l * 786432,          512, 512);
        transpose_w<<<dim3(16, 16), blk, 0, stream>>>(Wk + (size_t)l * 262144, qkvT + (size_t)l * 786432 + 262144, 512, 512);
        transpose_w<<<dim3(16, 16), blk, 0, stream>>>(Wv + (size_t)l * 262144, qkvT + (size_t)l * 786432 + 524288, 512, 512);
        transpose_w<<<dim3(16, 16), blk, 0, stream>>>(Wo + (size_t)l * 262144, woT + (size_t)l * 262144,           512, 512);
        transpose_w<<<dim3(64, 16), blk, 0, stream>>>(W1 + (size_t)l * 1048576, w1T + (size_t)l * 1048576,         512, 2048);
        transpose_w<<<dim3(16, 64), blk, 0, stream>>>(W2 + (size_t)l * 1048576, w2T + (size_t)l * 1048576,         2048, 512);
    }
    transpose_w<<<dim3(2, 16), blk, 0, stream>>>(Wp, wpT, 512, 64);
    concat_bias<<<12, blk, 0, stream>>>(bq, bk, bv, bqkv);
    pe_table<<<T_SEQ, blk, 0, stream>>>(pe);

    for (int b0 = 0; b0 < BATCH; b0 += Bg) {
        embed_kernel<<<rows * 2, blk, 0, stream>>>(x, E, pe, h, b0);

        for (int l = 0; l < 2; l++) {
            gemm_mx<2, false><<<dim3(nbm * 12), blk, 0, stream>>>(
                h, qkvT + (size_t)l * 786432, bqkv + l * 1536, nullptr, qkv,
                rows, 1536, 512, 1024, 12, 8);
            attn_chunk_sums<<<NCHUNK * BHg, blk, 0, stream>>>(qkv, Sb, Z, BHg);
            attn_prefix<<<BHg * 16, blk, 0, stream>>>(Sb, Z, BHg);
            attn_intra<<<NCHUNK * BHg, blk, 0, stream>>>(qkv, Sb, Z, am, BHg);
            gemm_mx<0, true><<<dim3(nbm * 4), blk, 0, stream>>>(
                am, woT + (size_t)l * 262144, bo + l * 512, h, o_,
                rows, 512, 512, 0, 4, 8);
            ln_kernel<<<rows / 4, blk, 0, stream>>>(o_, g1 + l * 512, be1 + l * 512, h);
            gemm_mx<1, false><<<dim3(nbm * 16), blk, 0, stream>>>(
                h, w1T + (size_t)l * 1048576, b1 + l * 2048, nullptr, ff1,
                rows, 2048, 512, 0, 16, 8);
            gemm_mx<0, true><<<dim3(nbm * 4), blk, 0, stream>>>(
                ff1, w2T + (size_t)l * 1048576, b2 + l * 512, h, am,
                rows, 512, 2048, 0, 4, 8);
            ln_kernel<<<rows / 4, blk, 0, stream>>>(am, g2 + l * 512, be2 + l * 512, h);
        }

        gemm_sm<64, 64, 2, 2><<<dim3(1, rows / 64), blk, 0, stream>>>(
            h, wpT, bp, (float*)d_out + (size_t)b0 * T_SEQ * 64, rows, 64, 512);
    }

    (void)in_sizes; (void)n_in; (void)out_size; (void)ws_size;
}

// Round 10
// 1607.151 us; speedup vs baseline: 1.1412x; 1.0548x over previous
//
#include <hip/hip_runtime.h>

// ---------------------------------------------------------------------------
// SequencePredictorRecurrentTransformer on MI355X (gfx950)
//
// I/O: fp32 (x int32). Internal: bf16 storage, fp32 accumulation.
// Layout [b][t][d] bt-major. Batch groups of Bg sized to ws_size.
//
// Round-10: attention loaders vectorized CORRECTLY (vs round-8's failure):
//  * uint4 global loads (8x fewer VMEM insts), uint4 LDS writes row-major.
//  * Transposed Kt/Vt use a SKEWED layout: (d,t) -> d*72 + ((t+8*(d>>3))&63).
//    Store bank = (4s + ((t+8m)&63)/2) mod 32: 2 lanes/bank = conflict-free,
//    with STATIC register indexing (round-8's dynamic u=s^m was the bug).
//    Reads stay 16B-aligned (skew is 8-granular; k-starts are mult of 8).
//  * attn_intra: Ps aliases Ks (dead after P-mfma; +1 barrier) ->
//    LDS 58->37.6 KB -> 4 blocks/CU (was 2).
// GEMMs unchanged (round-5 body, VGPR 88/96, XOR-swizzled DMA staging).
// ---------------------------------------------------------------------------

typedef unsigned short u16;
typedef __bf16 bf16x8 __attribute__((ext_vector_type(8)));
typedef float f32x4 __attribute__((ext_vector_type(4)));

#define T_SEQ 2048
#define BATCH 32
#define NHEADS 8
#define CT 64
#define NCHUNK 32             // T/CT

// skewed column offset for transposed LDS arrays (row r, t-index k)
#define SKEW(r, k) ((((k) + (((r) >> 3) << 3))) & 63)

__device__ __forceinline__ float b2f(u16 u) {
    union { unsigned int i; float f; } v; v.i = ((unsigned int)u) << 16; return v.f;
}
__device__ __forceinline__ u16 f2b(float f) {
    union { __bf16 b; u16 u; } v; v.b = (__bf16)f; return v.u;   // HW cvt, RNE
}

__device__ __forceinline__ void gl_lds16(const u16* g, u16* l) {
    __builtin_amdgcn_global_load_lds(
        (const __attribute__((address_space(1))) void*)g,
        (__attribute__((address_space(3))) void*)l,
        16, 0, 0);
}

// ---------------------------------------------------------------------------
// m97-structure GEMM (round-5 body): C[M,N] = act(A@BT^T + bias [+ R])
// BM=BN=128, BK=64, 4 waves x 64x64 acc. XOR-swizzled global_load_lds.
// ACT: 0=none, 1=relu, 2=phi(elu+1) where col < act_split.
// ---------------------------------------------------------------------------
template<int ACT, bool RES>
__global__ __launch_bounds__(256) void gemm_mx(
    const u16* __restrict__ A, const u16* __restrict__ BT,
    const float* __restrict__ bias, const u16* __restrict__ R,
    u16* __restrict__ C,
    int M, int N, int K, int act_split, int nbn, int GM)
{
    __shared__ __align__(16) u16 As[128 * 64];
    __shared__ __align__(16) u16 Bs[128 * 64];

    const int bid = blockIdx.x;
    const int gsz = GM * nbn;
    const int grp = bid / gsz, rm = bid % gsz;
    const int bm = (grp * GM + rm % GM) * 128;
    const int bn = (rm / GM) * 128;

    const int tid = threadIdx.x;
    const int lane = tid & 63;
    const int w = tid >> 6;
    const int lrow = lane & 15, quad = lane >> 4;
    const int wrow = (w >> 1) * 64, wcol = (w & 1) * 64;
    const int sr = lane >> 3;          // staging: row within 8-row chunk
    const int sg = lane & 7;           // staging: granule slot in row

    f32x4 acc[4][4] = {};

    for (int k0 = 0; k0 < K; k0 += 64) {
        #pragma unroll
        for (int ch4 = 0; ch4 < 4; ch4++) {
            const int chunk = w * 4 + ch4;        // 0..15 (8 rows each)
            const int r = chunk * 8 + sr;         // 0..127
            const int gs = sg ^ (r & 7);          // swizzled source granule
            gl_lds16(A  + (size_t)(bm + r) * K + k0 + gs * 8, As + chunk * 512);
            gl_lds16(BT + (size_t)(bn + r) * K + k0 + gs * 8, Bs + chunk * 512);
        }
        __syncthreads();
        #pragma unroll
        for (int half = 0; half < 2; half++) {
            bf16x8 af[4], bfv[4];
            #pragma unroll
            for (int i = 0; i < 4; i++) {
                const int r = wrow + i * 16 + lrow;
                const int gq = (half * 4 + quad) ^ (r & 7);
                af[i] = *(const bf16x8*)&As[r * 64 + gq * 8];
            }
            #pragma unroll
            for (int j = 0; j < 4; j++) {
                const int r = wcol + j * 16 + lrow;
                const int gq = (half * 4 + quad) ^ (r & 7);
                bfv[j] = *(const bf16x8*)&Bs[r * 64 + gq * 8];
            }
            #pragma unroll
            for (int i = 0; i < 4; i++)
                #pragma unroll
                for (int j = 0; j < 4; j++)
                    acc[i][j] = __builtin_amdgcn_mfma_f32_16x16x32_bf16(
                        af[i], bfv[j], acc[i][j], 0, 0, 0);
        }
        __syncthreads();
    }

    // Epilogue. D: col = lane&15, row = quad*4 + r.
    #pragma unroll
    for (int i = 0; i < 4; i++) {
        const int row0 = bm + wrow + i * 16 + quad * 4;
        #pragma unroll
        for (int j = 0; j < 4; j++) {
            const int col = bn + wcol + j * 16 + lrow;
            const float bb = bias[col];
            #pragma unroll
            for (int r = 0; r < 4; r++) {
                float v = acc[i][j][r] + bb;
                if (RES) v += b2f(R[(size_t)(row0 + r) * N + col]);
                if (ACT == 1) v = fmaxf(v, 0.f);
                if (ACT == 2) { if (col < act_split) v = (v > 0.f) ? (v + 1.f) : __expf(v); }
                C[(size_t)(row0 + r) * N + col] = f2b(v);
            }
        }
    }
}

// ---------------------------------------------------------------------------
// Small-N GEMM (final projection, N=64): fp32 out, swapped epilogue (16B st).
// ---------------------------------------------------------------------------
template<int BM, int BN, int WM, int WN>
__global__ __launch_bounds__(WM*WN*64) void gemm_sm(
    const u16* __restrict__ A, const u16* __restrict__ BT,
    const float* __restrict__ bias, float* __restrict__ C,
    int M, int N, int K)
{
    constexpr int BK = 32;
    constexpr int LDT = BK + 8;
    constexpr int NTHR = WM * WN * 64;
    __shared__ __align__(16) u16 As[BM * LDT];
    __shared__ __align__(16) u16 Bs[BN * LDT];

    const int tid = threadIdx.x;
    const int bm = blockIdx.y * BM;
    const int bn = blockIdx.x * BN;
    const int lane = tid & 63;
    const int wid = tid >> 6;
    const int wrow = (wid / WN) * (BM / WM);
    const int wcol = (wid % WN) * (BN / WN);
    constexpr int FM = BM / WM / 16;
    constexpr int FN = BN / WN / 16;
    const int lrow = lane & 15;
    const int lk = (lane >> 4) * 8;

    f32x4 acc[FM][FN] = {};

    for (int k0 = 0; k0 < K; k0 += BK) {
        #pragma unroll
        for (int g0 = 0; g0 < BM * 4; g0 += NTHR) {
            int g = g0 + tid;
            int row = g >> 2, kk = (g & 3) * 8;
            *(uint4*)&As[row * LDT + kk] =
                *(const uint4*)&A[(size_t)(bm + row) * K + k0 + kk];
        }
        #pragma unroll
        for (int g0 = 0; g0 < BN * 4; g0 += NTHR) {
            int g = g0 + tid;
            int row = g >> 2, kk = (g & 3) * 8;
            *(uint4*)&Bs[row * LDT + kk] =
                *(const uint4*)&BT[(size_t)(bn + row) * K + k0 + kk];
        }
        __syncthreads();
        bf16x8 af[FM], bfv[FN];
        #pragma unroll
        for (int i = 0; i < FM; i++)
            af[i] = *(const bf16x8*)&As[(wrow + i * 16 + lrow) * LDT + lk];
        #pragma unroll
        for (int j = 0; j < FN; j++)
            bfv[j] = *(const bf16x8*)&Bs[(wcol + j * 16 + lrow) * LDT + lk];
        #pragma unroll
        for (int i = 0; i < FM; i++)
            #pragma unroll
            for (int j = 0; j < FN; j++)
                acc[i][j] = __builtin_amdgcn_mfma_f32_16x16x32_bf16(
                    bfv[j], af[i], acc[i][j], 0, 0, 0);   // swapped
        __syncthreads();
    }

    #pragma unroll
    for (int i = 0; i < FM; i++) {
        const int row = bm + wrow + i * 16 + lrow;
        #pragma unroll
        for (int j = 0; j < FN; j++) {
            const int col0 = bn + wcol + j * 16 + (lane >> 4) * 4;
            const float4 bb = *(const float4*)&bias[col0];
            float4 o = { acc[i][j][0] + bb.x, acc[i][j][1] + bb.y,
                         acc[i][j][2] + bb.z, acc[i][j][3] + bb.w };
            *(float4*)&C[(size_t)row * N + col0] = o;
        }
    }
}

// ---------------------------------------------------------------------------
__global__ __launch_bounds__(256) void transpose_w(
    const float* __restrict__ src, u16* __restrict__ dst, int K, int N)
{
    __shared__ float tile[32][33];
    int bx = blockIdx.x, by = blockIdx.y;
    int tx = threadIdx.x & 31, ty = threadIdx.x >> 5;
    #pragma unroll
    for (int yy = 0; yy < 4; yy++) {
        int k = by * 32 + ty + yy * 8;
        tile[ty + yy * 8][tx] = src[(size_t)k * N + bx * 32 + tx];
    }
    __syncthreads();
    #pragma unroll
    for (int yy = 0; yy < 4; yy++) {
        int n = bx * 32 + ty + yy * 8;
        dst[(size_t)n * K + by * 32 + tx] = f2b(tile[tx][ty + yy * 8]);
    }
}

__global__ __launch_bounds__(256) void concat_bias(
    const float* __restrict__ bq, const float* __restrict__ bk,
    const float* __restrict__ bv, float* __restrict__ dst)
{
    int id = blockIdx.x * 256 + threadIdx.x;
    if (id >= 3072) return;
    int l = id / 1536, i = id % 1536;
    float v = (i < 512) ? bq[l * 512 + i]
            : (i < 1024) ? bk[l * 512 + i - 512]
                         : bv[l * 512 + i - 1024];
    dst[id] = v;
}

// ---------------------------------------------------------------------------
// PE table: pe[t][j] for t<2048, j<256 (bf16), computed once.
// ---------------------------------------------------------------------------
__global__ __launch_bounds__(256) void pe_table(u16* __restrict__ pe)
{
    int id = blockIdx.x * 256 + threadIdx.x;   // < 2048*256
    int t = id >> 8, j = id & 255;
    int i = j >> 1;
    float div = expf(-(float)(2 * i) * (9.210340371976184f / 256.f)); // ln(1e4)/256
    float arg = (float)t * div;
    pe[id] = f2b((j & 1) ? cosf(arg) : sinf(arg));
}

// ---------------------------------------------------------------------------
// Embedding (bt-major): pure gather from E and the PE table.
// ---------------------------------------------------------------------------
__global__ __launch_bounds__(256) void embed_kernel(
    const int* __restrict__ x, const float* __restrict__ E,
    const u16* __restrict__ pe, u16* __restrict__ h, int b0)
{
    int e = blockIdx.x * 256 + threadIdx.x;
    int r = e >> 9;
    int c = e & 511;
    int t = r & (T_SEQ - 1);
    int b = b0 + (r >> 11);
    u16 o;
    if (c < 256) o = f2b(E[x[t * BATCH + b] * 256 + c]);
    else         o = pe[t * 256 + (c - 256)];
    h[e] = o;
}

// ---------------------------------------------------------------------------
// Phase A (MFMA): S'_c[m][d] = sum_t V[t][m]*K[t][d] -> bf16; Z_c[d]=sum K.
// Loader: uint4 global; skewed transposed LDS stores (static reg indexing).
// ---------------------------------------------------------------------------
__global__ __launch_bounds__(256) void attn_chunk_sums(
    const u16* __restrict__ qkv, u16* __restrict__ S, float* __restrict__ Z,
    int BHg)
{
    __shared__ __align__(16) u16 Kt[64 * 72], Vt[64 * 72];   // skewed [d][t]
    int bid = blockIdx.x;
    int bh = bid % BHg, c = bid / BHg;
    int bl = bh >> 3, hh = bh & 7;
    {
        const int m  = threadIdx.x & 7;
        const int d0 = m * 8;
        #pragma unroll
        for (int p = 0; p < 2; p++) {
            const int t = p * 32 + (threadIdx.x >> 3);
            size_t rr = ((size_t)(bl * T_SEQ + c * 64 + t)) * 1536 + hh * 64 + d0;
            uint4 kv = *(const uint4*)&qkv[rr + 512];
            uint4 vv = *(const uint4*)&qkv[rr + 1024];
            const u16* kp = (const u16*)&kv;
            const u16* vp = (const u16*)&vv;
            const int sk = (t + d0) & 63;         // skew col for rows d0..d0+7
            u16* kb = &Kt[d0 * 72 + sk];
            u16* vb = &Vt[d0 * 72 + sk];
            #pragma unroll
            for (int s = 0; s < 8; s++) { kb[s * 72] = kp[s]; vb[s * 72] = vp[s]; }
        }
    }
    __syncthreads();
    int lane = threadIdx.x & 63;
    int w = threadIdx.x >> 6;
    int lrow = lane & 15, quad = lane >> 4;
    int m0 = w * 16;
    f32x4 acc[4] = {};
    #pragma unroll
    for (int k0 = 0; k0 < 64; k0 += 32) {
        const int ra = m0 + lrow;
        bf16x8 af = *(const bf16x8*)&Vt[ra * 72 + SKEW(ra, k0 + quad * 8)];
        #pragma unroll
        for (int jt = 0; jt < 4; jt++) {
            const int rb = jt * 16 + lrow;
            bf16x8 bf = *(const bf16x8*)&Kt[rb * 72 + SKEW(rb, k0 + quad * 8)];
            acc[jt] = __builtin_amdgcn_mfma_f32_16x16x32_bf16(bf, af, acc[jt], 0, 0, 0);
        }
    }
    size_t base = ((size_t)c * BHg + bh) * 4096;
    const int m = m0 + lrow;
    #pragma unroll
    for (int jt = 0; jt < 4; jt++) {
        const int d0 = jt * 16 + quad * 4;
        union { u16 q[4]; uint2 u; } pk;
        #pragma unroll
        for (int r = 0; r < 4; r++) pk.q[r] = f2b(acc[jt][r]);
        *(uint2*)&S[base + m * 64 + d0] = pk.u;
    }
    if (threadIdx.x < 64) {
        const int d = threadIdx.x;
        float z = 0.f;
        #pragma unroll
        for (int t8 = 0; t8 < 64; t8 += 8) {
            bf16x8 kk = *(const bf16x8*)&Kt[d * 72 + SKEW(d, t8)];
            #pragma unroll
            for (int u = 0; u < 8; u++) z += (float)kk[u];
        }
        Z[((size_t)c * BHg + bh) * 64 + d] = z;
    }
}

// ---------------------------------------------------------------------------
// Phase B: exclusive prefix over chunks; register scan, loads all in flight.
// ---------------------------------------------------------------------------
__global__ __launch_bounds__(256) void attn_prefix(
    u16* __restrict__ S, float* __restrict__ Z, int BHg)
{
    int gid = blockIdx.x * 256 + threadIdx.x;   // < BHg*4096
    int bh = gid >> 12, e = gid & 4095;
    size_t stride = (size_t)BHg * 4096;
    size_t base = (size_t)bh * 4096 + e;
    float v[NCHUNK];
    #pragma unroll
    for (int c = 0; c < NCHUNK; c++) v[c] = b2f(S[base + c * stride]);
    float run = 0.f;
    #pragma unroll
    for (int c = 0; c < NCHUNK; c++) {
        float t = v[c]; S[base + c * stride] = f2b(run); run += t;
    }
    if (gid < BHg * 64) {
        size_t zb = (size_t)gid;
        size_t zs = (size_t)BHg * 64;
        float zv[NCHUNK];
        #pragma unroll
        for (int c = 0; c < NCHUNK; c++) zv[c] = Z[zb + c * zs];
        float zr = 0.f;
        #pragma unroll
        for (int c = 0; c < NCHUNK; c++) {
            float t = zv[c]; Z[zb + c * zs] = zr; zr += t;
        }
    }
}

// ---------------------------------------------------------------------------
// Phase C (MFMA): P=QK^T masked; O=(P@V + Q@S')/den.
// Loader: uint4 global + uint4 row-major LDS; skewed Vt. Ps aliases Ks.
// ---------------------------------------------------------------------------
__global__ __launch_bounds__(256) void attn_intra(
    const u16* __restrict__ qkv, const u16* __restrict__ Sp,
    const float* __restrict__ Zp, u16* __restrict__ out, int BHg)
{
    __shared__ __align__(16) u16 Qs[64 * 72], Ks[64 * 72], Vt[64 * 72],
                                 Ssh[64 * 72];
    __shared__ float Zsh[64], den2sh[64], den1sh[64];
    u16* Ps = Ks;                              // Ks dead after P-mfma
    int bid = blockIdx.x;
    int bh = bid % BHg, c = bid / BHg;
    int bl = bh >> 3, hh = bh & 7;
    size_t sbase = ((size_t)c * BHg + bh) * 4096;
    {
        const int m  = threadIdx.x & 7;
        const int d0 = m * 8;
        #pragma unroll
        for (int p = 0; p < 2; p++) {
            const int t = p * 32 + (threadIdx.x >> 3);
            size_t rr = ((size_t)(bl * T_SEQ + c * 64 + t)) * 1536 + hh * 64 + d0;
            *(uint4*)&Qs[t * 72 + d0]  = *(const uint4*)&qkv[rr];
            *(uint4*)&Ks[t * 72 + d0]  = *(const uint4*)&qkv[rr + 512];
            *(uint4*)&Ssh[t * 72 + d0] = *(const uint4*)&Sp[sbase + t * 64 + d0];
            uint4 vv = *(const uint4*)&qkv[rr + 1024];
            const u16* vp = (const u16*)&vv;
            const int sk = (t + d0) & 63;
            u16* vb = &Vt[d0 * 72 + sk];
            #pragma unroll
            for (int s = 0; s < 8; s++) vb[s * 72] = vp[s];
        }
    }
    if (threadIdx.x < 64)
        Zsh[threadIdx.x] = Zp[((size_t)c * BHg + bh) * 64 + threadIdx.x];
    __syncthreads();

    if (threadIdx.x < 64) {
        float s = 0.f;
        #pragma unroll
        for (int d8 = 0; d8 < 64; d8 += 8) {
            bf16x8 qq = *(const bf16x8*)&Qs[threadIdx.x * 72 + d8];
            #pragma unroll
            for (int u = 0; u < 8; u++) s += (float)qq[u] * Zsh[d8 + u];
        }
        den2sh[threadIdx.x] = s;
    }

    int lane = threadIdx.x & 63;
    int w = threadIdx.x >> 6;
    int lrow = lane & 15, quad = lane >> 4;
    int i0 = w * 16;

    // P = Q @ K^T (row = i via reg)
    f32x4 accp[4] = {};
    #pragma unroll
    for (int k0 = 0; k0 < 64; k0 += 32) {
        bf16x8 af = *(const bf16x8*)&Qs[(i0 + lrow) * 72 + k0 + quad * 8];
        #pragma unroll
        for (int jt = 0; jt < 4; jt++) {
            bf16x8 bf = *(const bf16x8*)&Ks[(jt * 16 + lrow) * 72 + k0 + quad * 8];
            accp[jt] = __builtin_amdgcn_mfma_f32_16x16x32_bf16(af, bf, accp[jt], 0, 0, 0);
        }
    }
    __syncthreads();                           // all Ks reads done before Ps writes
    #pragma unroll
    for (int r = 0; r < 4; r++) {
        int row = i0 + quad * 4 + r;
        float d1 = 0.f;
        #pragma unroll
        for (int jt = 0; jt < 4; jt++) {
            int col = jt * 16 + lrow;
            float pv = (col <= row) ? accp[jt][r] : 0.f;
            d1 += pv;
            Ps[row * 72 + col] = f2b(pv);
        }
        #pragma unroll
        for (int off = 1; off < 16; off <<= 1)
            d1 += __shfl_xor(d1, off, 64);
        if (lrow == 0) den1sh[row] = d1;
    }
    __syncthreads();

    // O = Ps @ V + Q @ S'  (swapped: first operand = m side)
    f32x4 acco[4] = {};
    #pragma unroll
    for (int k0 = 0; k0 < 64; k0 += 32) {
        bf16x8 ps = *(const bf16x8*)&Ps[(i0 + lrow) * 72 + k0 + quad * 8];
        #pragma unroll
        for (int jt = 0; jt < 4; jt++) {
            const int rv = jt * 16 + lrow;
            bf16x8 vf = *(const bf16x8*)&Vt[rv * 72 + SKEW(rv, k0 + quad * 8)];
            acco[jt] = __builtin_amdgcn_mfma_f32_16x16x32_bf16(vf, ps, acco[jt], 0, 0, 0);
        }
    }
    #pragma unroll
    for (int k0 = 0; k0 < 64; k0 += 32) {
        bf16x8 qf = *(const bf16x8*)&Qs[(i0 + lrow) * 72 + k0 + quad * 8];
        #pragma unroll
        for (int jt = 0; jt < 4; jt++) {
            bf16x8 sf = *(const bf16x8*)&Ssh[(jt * 16 + lrow) * 72 + k0 + quad * 8];
            acco[jt] = __builtin_amdgcn_mfma_f32_16x16x32_bf16(sf, qf, acco[jt], 0, 0, 0);
        }
    }
    const int i = i0 + lrow;
    const float inv = 1.f / (den1sh[i] + den2sh[i] + 1e-6f);
    size_t orow = ((size_t)(bl * T_SEQ + c * 64 + i)) * 512 + hh * 64;
    #pragma unroll
    for (int jt = 0; jt < 4; jt++) {
        const int m0 = jt * 16 + quad * 4;
        union { u16 q[4]; uint2 u; } pk;
        #pragma unroll
        for (int r = 0; r < 4; r++) pk.q[r] = f2b(acco[jt][r] * inv);
        *(uint2*)&out[orow + m0] = pk.u;
    }
}

// ---------------------------------------------------------------------------
// LayerNorm (single input stream; residual pre-added in GEMM epilogue).
// ---------------------------------------------------------------------------
__global__ __launch_bounds__(256) void ln_kernel(
    const u16* __restrict__ s_in,
    const float* __restrict__ g, const float* __restrict__ be, u16* __restrict__ out)
{
    int row = blockIdx.x * 4 + (threadIdx.x >> 6);
    int lane = threadIdx.x & 63;
    size_t base = (size_t)row * 512 + lane * 8;
    uint4 hv = *(const uint4*)&s_in[base];
    const u16* hp = (const u16*)&hv;
    float x[8]; float s = 0.f;
    #pragma unroll
    for (int i = 0; i < 8; i++) { x[i] = b2f(hp[i]); s += x[i]; }
    #pragma unroll
    for (int off = 32; off > 0; off >>= 1) s += __shfl_xor(s, off, 64);
    float m = s * (1.f / 512.f);
    float vs = 0.f;
    #pragma unroll
    for (int i = 0; i < 8; i++) { float t = x[i] - m; vs += t * t; }
    #pragma unroll
    for (int off = 32; off > 0; off >>= 1) vs += __shfl_xor(vs, off, 64);
    float rstd = rsqrtf(vs * (1.f / 512.f) + 1e-5f);
    union { u16 u[8]; uint4 v; } o;
    #pragma unroll
    for (int i = 0; i < 8; i++)
        o.u[i] = f2b((x[i] - m) * rstd * g[lane * 8 + i] + be[lane * 8 + i]);
    *(uint4*)&out[base] = o.v;
}

// ---------------------------------------------------------------------------
extern "C" void kernel_launch(void* const* d_in, const int* in_sizes, int n_in,
                              void* d_out, int out_size, void* d_ws, size_t ws_size,
                              hipStream_t stream)
{
    const int*   x  = (const int*)d_in[0];
    const float* E  = (const float*)d_in[1];
    const float* Wq = (const float*)d_in[2];
    const float* bq = (const float*)d_in[3];
    const float* Wk = (const float*)d_in[4];
    const float* bk = (const float*)d_in[5];
    const float* Wv = (const float*)d_in[6];
    const float* bv = (const float*)d_in[7];
    const float* Wo = (const float*)d_in[8];
    const float* bo = (const float*)d_in[9];
    const float* g1 = (const float*)d_in[10];
    const float* be1= (const float*)d_in[11];
    const float* W1 = (const float*)d_in[12];
    const float* b1 = (const float*)d_in[13];
    const float* W2 = (const float*)d_in[14];
    const float* b2 = (const float*)d_in[15];
    const float* g2 = (const float*)d_in[16];
    const float* be2= (const float*)d_in[17];
    const float* Wp = (const float*)d_in[18];
    const float* bp = (const float*)d_in[19];

    // --- fixed region: bf16 transposed weights + PE table + fp32 qkv bias ---
    char* p = (char*)d_ws;
    u16* qkvT = (u16*)p; p += (size_t)2 * 1536 * 512 * 2;
    u16* woT  = (u16*)p; p += (size_t)2 * 512 * 512 * 2;
    u16* w1T  = (u16*)p; p += (size_t)2 * 2048 * 512 * 2;
    u16* w2T  = (u16*)p; p += (size_t)2 * 512 * 2048 * 2;
    u16* wpT  = (u16*)p; p += (size_t)64 * 512 * 2;
    u16* pe   = (u16*)p; p += (size_t)T_SEQ * 256 * 2;     // 1 MiB
    float* bqkv = (float*)p; p += (size_t)16384;
    size_t fixed = (size_t)(p - (char*)d_ws);

    // --- adaptive batch group: Bg * 12.65 MiB ---
    const size_t perB = 12648448ULL;
    int Bg = 32;
    while (Bg > 1 && fixed + (size_t)Bg * perB > ws_size) Bg >>= 1;
    const int rows = Bg * T_SEQ;
    const int BHg = Bg * NHEADS;
    const int nbm = rows / 128;

    u16* h      = (u16*)p; p += (size_t)rows * 512 * 2;
    u16* qkvBig = (u16*)p; p += (size_t)rows * 2048 * 2;
    u16* am     = (u16*)p; p += (size_t)rows * 512 * 2;
    float* Z    = (float*)p; p += (size_t)BHg * NCHUNK * 64 * 4;
    u16* qkv = qkvBig;                        // rows x 1536 during attention
    u16* Sb  = qkvBig + (size_t)rows * 1536;  // bf16 S' tail
    u16* ff1 = qkvBig;                        // rows x 2048 during FF
    u16* o_  = qkvBig;                        // rows x 512 Wo output (h+attn)

    dim3 blk(256);

    for (int l = 0; l < 2; l++) {
        transpose_w<<<dim3(16, 16), blk, 0, stream>>>(Wq + (size_t)l * 262144, qkvT + (size_t)l * 786432,          512, 512);
        transpose_w<<<dim3(16, 16), blk, 0, stream>>>(Wk + (size_t)l * 262144, qkvT + (size_t)l * 786432 + 262144, 512, 512);
        transpose_w<<<dim3(16, 16), blk, 0, stream>>>(Wv + (size_t)l * 262144, qkvT + (size_t)l * 786432 + 524288, 512, 512);
        transpose_w<<<dim3(16, 16), blk, 0, stream>>>(Wo + (size_t)l * 262144, woT + (size_t)l * 262144,           512, 512);
        transpose_w<<<dim3(64, 16), blk, 0, stream>>>(W1 + (size_t)l * 1048576, w1T + (size_t)l * 1048576,         512, 2048);
        transpose_w<<<dim3(16, 64), blk, 0, stream>>>(W2 + (size_t)l * 1048576, w2T + (size_t)l * 1048576,         2048, 512);
    }
    transpose_w<<<dim3(2, 16), blk, 0, stream>>>(Wp, wpT, 512, 64);
    concat_bias<<<12, blk, 0, stream>>>(bq, bk, bv, bqkv);
    pe_table<<<T_SEQ, blk, 0, stream>>>(pe);

    for (int b0 = 0; b0 < BATCH; b0 += Bg) {
        embed_kernel<<<rows * 2, blk, 0, stream>>>(x, E, pe, h, b0);

        for (int l = 0; l < 2; l++) {
            gemm_mx<2, false><<<dim3(nbm * 12), blk, 0, stream>>>(
                h, qkvT + (size_t)l * 786432, bqkv + l * 1536, nullptr, qkv,
                rows, 1536, 512, 1024, 12, 8);
            attn_chunk_sums<<<NCHUNK * BHg, blk, 0, stream>>>(qkv, Sb, Z, BHg);
            attn_prefix<<<BHg * 16, blk, 0, stream>>>(Sb, Z, BHg);
            attn_intra<<<NCHUNK * BHg, blk, 0, stream>>>(qkv, Sb, Z, am, BHg);
            gemm_mx<0, true><<<dim3(nbm * 4), blk, 0, stream>>>(
                am, woT + (size_t)l * 262144, bo + l * 512, h, o_,
                rows, 512, 512, 0, 4, 8);
            ln_kernel<<<rows / 4, blk, 0, stream>>>(o_, g1 + l * 512, be1 + l * 512, h);
            gemm_mx<1, false><<<dim3(nbm * 16), blk, 0, stream>>>(
                h, w1T + (size_t)l * 1048576, b1 + l * 2048, nullptr, ff1,
                rows, 2048, 512, 0, 16, 8);
            gemm_mx<0, true><<<dim3(nbm * 4), blk, 0, stream>>>(
                ff1, w2T + (size_t)l * 1048576, b2 + l * 512, h, am,
                rows, 512, 2048, 0, 4, 8);
            ln_kernel<<<rows / 4, blk, 0, stream>>>(am, g2 + l * 512, be2 + l * 512, h);
        }

        gemm_sm<64, 64, 2, 2><<<dim3(1, rows / 64), blk, 0, stream>>>(
            h, wpT, bp, (float*)d_out + (size_t)b0 * T_SEQ * 64, rows, 64, 512);
    }

    (void)in_sizes; (void)n_in; (void)out_size; (void)ws_size;
}

// Round 11
// 1561.409 us; speedup vs baseline: 1.1747x; 1.0293x over previous
//
#include <hip/hip_runtime.h>

// ---------------------------------------------------------------------------
// SequencePredictorRecurrentTransformer on MI355X (gfx950)
//
// I/O: fp32 (x int32). Internal: bf16 storage, fp32 accumulation.
// Layout [b][t][d] bt-major. Batch groups of Bg sized to ws_size.
//
// Round-11: merge the 15 preprocessing dispatches (13 weight transposes +
// concat_bias + pe_table) into ONE prep_kernel (block-uniform range switch;
// identical math). Saves ~14 dispatch gaps at ~2-3us each plus tiny-kernel
// underutilization. Everything else identical to round 10 (1607us):
//  * gemm_mx: m97-structure, XOR-swizzled global_load_lds, VGPR 88/96.
//  * attention: skewed-LDS vectorized loaders, Ps aliases Ks.
// ---------------------------------------------------------------------------

typedef unsigned short u16;
typedef __bf16 bf16x8 __attribute__((ext_vector_type(8)));
typedef float f32x4 __attribute__((ext_vector_type(4)));

#define T_SEQ 2048
#define BATCH 32
#define NHEADS 8
#define CT 64
#define NCHUNK 32             // T/CT

// skewed column offset for transposed LDS arrays (row r, t-index k)
#define SKEW(r, k) ((((k) + (((r) >> 3) << 3))) & 63)

__device__ __forceinline__ float b2f(u16 u) {
    union { unsigned int i; float f; } v; v.i = ((unsigned int)u) << 16; return v.f;
}
__device__ __forceinline__ u16 f2b(float f) {
    union { __bf16 b; u16 u; } v; v.b = (__bf16)f; return v.u;   // HW cvt, RNE
}

__device__ __forceinline__ void gl_lds16(const u16* g, u16* l) {
    __builtin_amdgcn_global_load_lds(
        (const __attribute__((address_space(1))) void*)g,
        (__attribute__((address_space(3))) void*)l,
        16, 0, 0);
}

// ---------------------------------------------------------------------------
// m97-structure GEMM (round-5 body): C[M,N] = act(A@BT^T + bias [+ R])
// BM=BN=128, BK=64, 4 waves x 64x64 acc. XOR-swizzled global_load_lds.
// ACT: 0=none, 1=relu, 2=phi(elu+1) where col < act_split.
// ---------------------------------------------------------------------------
template<int ACT, bool RES>
__global__ __launch_bounds__(256) void gemm_mx(
    const u16* __restrict__ A, const u16* __restrict__ BT,
    const float* __restrict__ bias, const u16* __restrict__ R,
    u16* __restrict__ C,
    int M, int N, int K, int act_split, int nbn, int GM)
{
    __shared__ __align__(16) u16 As[128 * 64];
    __shared__ __align__(16) u16 Bs[128 * 64];

    const int bid = blockIdx.x;
    const int gsz = GM * nbn;
    const int grp = bid / gsz, rm = bid % gsz;
    const int bm = (grp * GM + rm % GM) * 128;
    const int bn = (rm / GM) * 128;

    const int tid = threadIdx.x;
    const int lane = tid & 63;
    const int w = tid >> 6;
    const int lrow = lane & 15, quad = lane >> 4;
    const int wrow = (w >> 1) * 64, wcol = (w & 1) * 64;
    const int sr = lane >> 3;          // staging: row within 8-row chunk
    const int sg = lane & 7;           // staging: granule slot in row

    f32x4 acc[4][4] = {};

    for (int k0 = 0; k0 < K; k0 += 64) {
        #pragma unroll
        for (int ch4 = 0; ch4 < 4; ch4++) {
            const int chunk = w * 4 + ch4;        // 0..15 (8 rows each)
            const int r = chunk * 8 + sr;         // 0..127
            const int gs = sg ^ (r & 7);          // swizzled source granule
            gl_lds16(A  + (size_t)(bm + r) * K + k0 + gs * 8, As + chunk * 512);
            gl_lds16(BT + (size_t)(bn + r) * K + k0 + gs * 8, Bs + chunk * 512);
        }
        __syncthreads();
        #pragma unroll
        for (int half = 0; half < 2; half++) {
            bf16x8 af[4], bfv[4];
            #pragma unroll
            for (int i = 0; i < 4; i++) {
                const int r = wrow + i * 16 + lrow;
                const int gq = (half * 4 + quad) ^ (r & 7);
                af[i] = *(const bf16x8*)&As[r * 64 + gq * 8];
            }
            #pragma unroll
            for (int j = 0; j < 4; j++) {
                const int r = wcol + j * 16 + lrow;
                const int gq = (half * 4 + quad) ^ (r & 7);
                bfv[j] = *(const bf16x8*)&Bs[r * 64 + gq * 8];
            }
            #pragma unroll
            for (int i = 0; i < 4; i++)
                #pragma unroll
                for (int j = 0; j < 4; j++)
                    acc[i][j] = __builtin_amdgcn_mfma_f32_16x16x32_bf16(
                        af[i], bfv[j], acc[i][j], 0, 0, 0);
        }
        __syncthreads();
    }

    // Epilogue. D: col = lane&15, row = quad*4 + r.
    #pragma unroll
    for (int i = 0; i < 4; i++) {
        const int row0 = bm + wrow + i * 16 + quad * 4;
        #pragma unroll
        for (int j = 0; j < 4; j++) {
            const int col = bn + wcol + j * 16 + lrow;
            const float bb = bias[col];
            #pragma unroll
            for (int r = 0; r < 4; r++) {
                float v = acc[i][j][r] + bb;
                if (RES) v += b2f(R[(size_t)(row0 + r) * N + col]);
                if (ACT == 1) v = fmaxf(v, 0.f);
                if (ACT == 2) { if (col < act_split) v = (v > 0.f) ? (v + 1.f) : __expf(v); }
                C[(size_t)(row0 + r) * N + col] = f2b(v);
            }
        }
    }
}

// ---------------------------------------------------------------------------
// Small-N GEMM (final projection, N=64): fp32 out, swapped epilogue (16B st).
// ---------------------------------------------------------------------------
template<int BM, int BN, int WM, int WN>
__global__ __launch_bounds__(WM*WN*64) void gemm_sm(
    const u16* __restrict__ A, const u16* __restrict__ BT,
    const float* __restrict__ bias, float* __restrict__ C,
    int M, int N, int K)
{
    constexpr int BK = 32;
    constexpr int LDT = BK + 8;
    constexpr int NTHR = WM * WN * 64;
    __shared__ __align__(16) u16 As[BM * LDT];
    __shared__ __align__(16) u16 Bs[BN * LDT];

    const int tid = threadIdx.x;
    const int bm = blockIdx.y * BM;
    const int bn = blockIdx.x * BN;
    const int lane = tid & 63;
    const int wid = tid >> 6;
    const int wrow = (wid / WN) * (BM / WM);
    const int wcol = (wid % WN) * (BN / WN);
    constexpr int FM = BM / WM / 16;
    constexpr int FN = BN / WN / 16;
    const int lrow = lane & 15;
    const int lk = (lane >> 4) * 8;

    f32x4 acc[FM][FN] = {};

    for (int k0 = 0; k0 < K; k0 += BK) {
        #pragma unroll
        for (int g0 = 0; g0 < BM * 4; g0 += NTHR) {
            int g = g0 + tid;
            int row = g >> 2, kk = (g & 3) * 8;
            *(uint4*)&As[row * LDT + kk] =
                *(const uint4*)&A[(size_t)(bm + row) * K + k0 + kk];
        }
        #pragma unroll
        for (int g0 = 0; g0 < BN * 4; g0 += NTHR) {
            int g = g0 + tid;
            int row = g >> 2, kk = (g & 3) * 8;
            *(uint4*)&Bs[row * LDT + kk] =
                *(const uint4*)&BT[(size_t)(bn + row) * K + k0 + kk];
        }
        __syncthreads();
        bf16x8 af[FM], bfv[FN];
        #pragma unroll
        for (int i = 0; i < FM; i++)
            af[i] = *(const bf16x8*)&As[(wrow + i * 16 + lrow) * LDT + lk];
        #pragma unroll
        for (int j = 0; j < FN; j++)
            bfv[j] = *(const bf16x8*)&Bs[(wcol + j * 16 + lrow) * LDT + lk];
        #pragma unroll
        for (int i = 0; i < FM; i++)
            #pragma unroll
            for (int j = 0; j < FN; j++)
                acc[i][j] = __builtin_amdgcn_mfma_f32_16x16x32_bf16(
                    bfv[j], af[i], acc[i][j], 0, 0, 0);   // swapped
        __syncthreads();
    }

    #pragma unroll
    for (int i = 0; i < FM; i++) {
        const int row = bm + wrow + i * 16 + lrow;
        #pragma unroll
        for (int j = 0; j < FN; j++) {
            const int col0 = bn + wcol + j * 16 + (lane >> 4) * 4;
            const float4 bb = *(const float4*)&bias[col0];
            float4 o = { acc[i][j][0] + bb.x, acc[i][j][1] + bb.y,
                         acc[i][j][2] + bb.z, acc[i][j][3] + bb.w };
            *(float4*)&C[(size_t)row * N + col0] = o;
        }
    }
}

// ---------------------------------------------------------------------------
// Mega-preprocess: ALL weight transposes (fp32->bf16) + PE table + qkv bias
// concat in ONE dispatch. Block ranges (block-uniform branches, no divergence):
//   [0,1536)    Wq/Wk/Wv -> qkvT   (512x512, 256 tiles each, 2 layers)
//   [1536,2048) Wo -> woT          (512x512)
//   [2048,4096) W1 -> w1T          (K=512,N=2048, 1024 tiles/layer)
//   [4096,6144) W2 -> w2T          (K=2048,N=512)
//   [6144,6176) Wp -> wpT          (K=512,N=64, 32 tiles)
//   [6176,8224) pe table           (2048 blocks)
//   [8224,8236) bias concat        (12 blocks)
// ---------------------------------------------------------------------------
__global__ __launch_bounds__(256) void prep_kernel(
    const float* __restrict__ Wq, const float* __restrict__ Wk,
    const float* __restrict__ Wv, const float* __restrict__ Wo,
    const float* __restrict__ W1, const float* __restrict__ W2,
    const float* __restrict__ Wp,
    const float* __restrict__ bq, const float* __restrict__ bk,
    const float* __restrict__ bv,
    u16* __restrict__ qkvT, u16* __restrict__ woT, u16* __restrict__ w1T,
    u16* __restrict__ w2T, u16* __restrict__ wpT, u16* __restrict__ pe,
    float* __restrict__ bqkv)
{
    __shared__ float tile[32][33];
    const int bid = blockIdx.x;
    const float* src; u16* dst; int K, N, bx, by;

    if (bid < 1536) {
        int l = bid / 768, r = bid % 768, m = r >> 8, t = r & 255;
        const float* s3[3] = { Wq, Wk, Wv };            // m block-uniform
        src = s3[m] + (size_t)l * 262144;
        dst = qkvT + (size_t)l * 786432 + (size_t)m * 262144;
        K = 512; N = 512; bx = t & 15; by = t >> 4;
    } else if (bid < 2048) {
        int r = bid - 1536, l = r >> 8, t = r & 255;
        src = Wo + (size_t)l * 262144; dst = woT + (size_t)l * 262144;
        K = 512; N = 512; bx = t & 15; by = t >> 4;
    } else if (bid < 4096) {
        int r = bid - 2048, l = r >> 10, t = r & 1023;
        src = W1 + (size_t)l * 1048576; dst = w1T + (size_t)l * 1048576;
        K = 512; N = 2048; bx = t & 63; by = t >> 6;
    } else if (bid < 6144) {
        int r = bid - 4096, l = r >> 10, t = r & 1023;
        src = W2 + (size_t)l * 1048576; dst = w2T + (size_t)l * 1048576;
        K = 2048; N = 512; bx = t & 15; by = t >> 4;
    } else if (bid < 6176) {
        int t = bid - 6144;
        src = Wp; dst = wpT; K = 512; N = 64; bx = t & 1; by = t >> 1;
    } else if (bid < 8224) {
        int id = (bid - 6176) * 256 + threadIdx.x;      // < 2048*256
        int t = id >> 8, j = id & 255;
        int i = j >> 1;
        float div = expf(-(float)(2 * i) * (9.210340371976184f / 256.f));
        float arg = (float)t * div;
        pe[id] = f2b((j & 1) ? cosf(arg) : sinf(arg));
        return;
    } else {
        int id = (bid - 8224) * 256 + threadIdx.x;
        if (id < 3072) {
            int l = id / 1536, i2 = id % 1536;
            float v = (i2 < 512) ? bq[l * 512 + i2]
                    : (i2 < 1024) ? bk[l * 512 + i2 - 512]
                                  : bv[l * 512 + i2 - 1024];
            bqkv[id] = v;
        }
        return;
    }

    // 32x32 transpose tile: dst[N][K] = bf16(src[K][N])
    int tx = threadIdx.x & 31, ty = threadIdx.x >> 5;
    #pragma unroll
    for (int yy = 0; yy < 4; yy++) {
        int k = by * 32 + ty + yy * 8;
        tile[ty + yy * 8][tx] = src[(size_t)k * N + bx * 32 + tx];
    }
    __syncthreads();
    #pragma unroll
    for (int yy = 0; yy < 4; yy++) {
        int n = bx * 32 + ty + yy * 8;
        dst[(size_t)n * K + by * 32 + tx] = f2b(tile[tx][ty + yy * 8]);
    }
}

// ---------------------------------------------------------------------------
// Embedding (bt-major): pure gather from E and the PE table.
// ---------------------------------------------------------------------------
__global__ __launch_bounds__(256) void embed_kernel(
    const int* __restrict__ x, const float* __restrict__ E,
    const u16* __restrict__ pe, u16* __restrict__ h, int b0)
{
    int e = blockIdx.x * 256 + threadIdx.x;
    int r = e >> 9;
    int c = e & 511;
    int t = r & (T_SEQ - 1);
    int b = b0 + (r >> 11);
    u16 o;
    if (c < 256) o = f2b(E[x[t * BATCH + b] * 256 + c]);
    else         o = pe[t * 256 + (c - 256)];
    h[e] = o;
}

// ---------------------------------------------------------------------------
// Phase A (MFMA): S'_c[m][d] = sum_t V[t][m]*K[t][d] -> bf16; Z_c[d]=sum K.
// Loader: uint4 global; skewed transposed LDS stores (static reg indexing).
// ---------------------------------------------------------------------------
__global__ __launch_bounds__(256) void attn_chunk_sums(
    const u16* __restrict__ qkv, u16* __restrict__ S, float* __restrict__ Z,
    int BHg)
{
    __shared__ __align__(16) u16 Kt[64 * 72], Vt[64 * 72];   // skewed [d][t]
    int bid = blockIdx.x;
    int bh = bid % BHg, c = bid / BHg;
    int bl = bh >> 3, hh = bh & 7;
    {
        const int m  = threadIdx.x & 7;
        const int d0 = m * 8;
        #pragma unroll
        for (int p = 0; p < 2; p++) {
            const int t = p * 32 + (threadIdx.x >> 3);
            size_t rr = ((size_t)(bl * T_SEQ + c * 64 + t)) * 1536 + hh * 64 + d0;
            uint4 kv = *(const uint4*)&qkv[rr + 512];
            uint4 vv = *(const uint4*)&qkv[rr + 1024];
            const u16* kp = (const u16*)&kv;
            const u16* vp = (const u16*)&vv;
            const int sk = (t + d0) & 63;         // skew col for rows d0..d0+7
            u16* kb = &Kt[d0 * 72 + sk];
            u16* vb = &Vt[d0 * 72 + sk];
            #pragma unroll
            for (int s = 0; s < 8; s++) { kb[s * 72] = kp[s]; vb[s * 72] = vp[s]; }
        }
    }
    __syncthreads();
    int lane = threadIdx.x & 63;
    int w = threadIdx.x >> 6;
    int lrow = lane & 15, quad = lane >> 4;
    int m0 = w * 16;
    f32x4 acc[4] = {};
    #pragma unroll
    for (int k0 = 0; k0 < 64; k0 += 32) {
        const int ra = m0 + lrow;
        bf16x8 af = *(const bf16x8*)&Vt[ra * 72 + SKEW(ra, k0 + quad * 8)];
        #pragma unroll
        for (int jt = 0; jt < 4; jt++) {
            const int rb = jt * 16 + lrow;
            bf16x8 bf = *(const bf16x8*)&Kt[rb * 72 + SKEW(rb, k0 + quad * 8)];
            acc[jt] = __builtin_amdgcn_mfma_f32_16x16x32_bf16(bf, af, acc[jt], 0, 0, 0);
        }
    }
    size_t base = ((size_t)c * BHg + bh) * 4096;
    const int m = m0 + lrow;
    #pragma unroll
    for (int jt = 0; jt < 4; jt++) {
        const int d0 = jt * 16 + quad * 4;
        union { u16 q[4]; uint2 u; } pk;
        #pragma unroll
        for (int r = 0; r < 4; r++) pk.q[r] = f2b(acc[jt][r]);
        *(uint2*)&S[base + m * 64 + d0] = pk.u;
    }
    if (threadIdx.x < 64) {
        const int d = threadIdx.x;
        float z = 0.f;
        #pragma unroll
        for (int t8 = 0; t8 < 64; t8 += 8) {
            bf16x8 kk = *(const bf16x8*)&Kt[d * 72 + SKEW(d, t8)];
            #pragma unroll
            for (int u = 0; u < 8; u++) z += (float)kk[u];
        }
        Z[((size_t)c * BHg + bh) * 64 + d] = z;
    }
}

// ---------------------------------------------------------------------------
// Phase B: exclusive prefix over chunks; register scan, loads all in flight.
// ---------------------------------------------------------------------------
__global__ __launch_bounds__(256) void attn_prefix(
    u16* __restrict__ S, float* __restrict__ Z, int BHg)
{
    int gid = blockIdx.x * 256 + threadIdx.x;   // < BHg*4096
    int bh = gid >> 12, e = gid & 4095;
    size_t stride = (size_t)BHg * 4096;
    size_t base = (size_t)bh * 4096 + e;
    float v[NCHUNK];
    #pragma unroll
    for (int c = 0; c < NCHUNK; c++) v[c] = b2f(S[base + c * stride]);
    float run = 0.f;
    #pragma unroll
    for (int c = 0; c < NCHUNK; c++) {
        float t = v[c]; S[base + c * stride] = f2b(run); run += t;
    }
    if (gid < BHg * 64) {
        size_t zb = (size_t)gid;
        size_t zs = (size_t)BHg * 64;
        float zv[NCHUNK];
        #pragma unroll
        for (int c = 0; c < NCHUNK; c++) zv[c] = Z[zb + c * zs];
        float zr = 0.f;
        #pragma unroll
        for (int c = 0; c < NCHUNK; c++) {
            float t = zv[c]; Z[zb + c * zs] = zr; zr += t;
        }
    }
}

// ---------------------------------------------------------------------------
// Phase C (MFMA): P=QK^T masked; O=(P@V + Q@S')/den.
// Loader: uint4 global + uint4 row-major LDS; skewed Vt. Ps aliases Ks.
// ---------------------------------------------------------------------------
__global__ __launch_bounds__(256) void attn_intra(
    const u16* __restrict__ qkv, const u16* __restrict__ Sp,
    const float* __restrict__ Zp, u16* __restrict__ out, int BHg)
{
    __shared__ __align__(16) u16 Qs[64 * 72], Ks[64 * 72], Vt[64 * 72],
                                 Ssh[64 * 72];
    __shared__ float Zsh[64], den2sh[64], den1sh[64];
    u16* Ps = Ks;                              // Ks dead after P-mfma
    int bid = blockIdx.x;
    int bh = bid % BHg, c = bid / BHg;
    int bl = bh >> 3, hh = bh & 7;
    size_t sbase = ((size_t)c * BHg + bh) * 4096;
    {
        const int m  = threadIdx.x & 7;
        const int d0 = m * 8;
        #pragma unroll
        for (int p = 0; p < 2; p++) {
            const int t = p * 32 + (threadIdx.x >> 3);
            size_t rr = ((size_t)(bl * T_SEQ + c * 64 + t)) * 1536 + hh * 64 + d0;
            *(uint4*)&Qs[t * 72 + d0]  = *(const uint4*)&qkv[rr];
            *(uint4*)&Ks[t * 72 + d0]  = *(const uint4*)&qkv[rr + 512];
            *(uint4*)&Ssh[t * 72 + d0] = *(const uint4*)&Sp[sbase + t * 64 + d0];
            uint4 vv = *(const uint4*)&qkv[rr + 1024];
            const u16* vp = (const u16*)&vv;
            const int sk = (t + d0) & 63;
            u16* vb = &Vt[d0 * 72 + sk];
            #pragma unroll
            for (int s = 0; s < 8; s++) vb[s * 72] = vp[s];
        }
    }
    if (threadIdx.x < 64)
        Zsh[threadIdx.x] = Zp[((size_t)c * BHg + bh) * 64 + threadIdx.x];
    __syncthreads();

    if (threadIdx.x < 64) {
        float s = 0.f;
        #pragma unroll
        for (int d8 = 0; d8 < 64; d8 += 8) {
            bf16x8 qq = *(const bf16x8*)&Qs[threadIdx.x * 72 + d8];
            #pragma unroll
            for (int u = 0; u < 8; u++) s += (float)qq[u] * Zsh[d8 + u];
        }
        den2sh[threadIdx.x] = s;
    }

    int lane = threadIdx.x & 63;
    int w = threadIdx.x >> 6;
    int lrow = lane & 15, quad = lane >> 4;
    int i0 = w * 16;

    // P = Q @ K^T (row = i via reg)
    f32x4 accp[4] = {};
    #pragma unroll
    for (int k0 = 0; k0 < 64; k0 += 32) {
        bf16x8 af = *(const bf16x8*)&Qs[(i0 + lrow) * 72 + k0 + quad * 8];
        #pragma unroll
        for (int jt = 0; jt < 4; jt++) {
            bf16x8 bf = *(const bf16x8*)&Ks[(jt * 16 + lrow) * 72 + k0 + quad * 8];
            accp[jt] = __builtin_amdgcn_mfma_f32_16x16x32_bf16(af, bf, accp[jt], 0, 0, 0);
        }
    }
    __syncthreads();                           // all Ks reads done before Ps writes
    #pragma unroll
    for (int r = 0; r < 4; r++) {
        int row = i0 + quad * 4 + r;
        float d1 = 0.f;
        #pragma unroll
        for (int jt = 0; jt < 4; jt++) {
            int col = jt * 16 + lrow;
            float pv = (col <= row) ? accp[jt][r] : 0.f;
            d1 += pv;
            Ps[row * 72 + col] = f2b(pv);
        }
        #pragma unroll
        for (int off = 1; off < 16; off <<= 1)
            d1 += __shfl_xor(d1, off, 64);
        if (lrow == 0) den1sh[row] = d1;
    }
    __syncthreads();

    // O = Ps @ V + Q @ S'  (swapped: first operand = m side)
    f32x4 acco[4] = {};
    #pragma unroll
    for (int k0 = 0; k0 < 64; k0 += 32) {
        bf16x8 ps = *(const bf16x8*)&Ps[(i0 + lrow) * 72 + k0 + quad * 8];
        #pragma unroll
        for (int jt = 0; jt < 4; jt++) {
            const int rv = jt * 16 + lrow;
            bf16x8 vf = *(const bf16x8*)&Vt[rv * 72 + SKEW(rv, k0 + quad * 8)];
            acco[jt] = __builtin_amdgcn_mfma_f32_16x16x32_bf16(vf, ps, acco[jt], 0, 0, 0);
        }
    }
    #pragma unroll
    for (int k0 = 0; k0 < 64; k0 += 32) {
        bf16x8 qf = *(const bf16x8*)&Qs[(i0 + lrow) * 72 + k0 + quad * 8];
        #pragma unroll
        for (int jt = 0; jt < 4; jt++) {
            bf16x8 sf = *(const bf16x8*)&Ssh[(jt * 16 + lrow) * 72 + k0 + quad * 8];
            acco[jt] = __builtin_amdgcn_mfma_f32_16x16x32_bf16(sf, qf, acco[jt], 0, 0, 0);
        }
    }
    const int i = i0 + lrow;
    const float inv = 1.f / (den1sh[i] + den2sh[i] + 1e-6f);
    size_t orow = ((size_t)(bl * T_SEQ + c * 64 + i)) * 512 + hh * 64;
    #pragma unroll
    for (int jt = 0; jt < 4; jt++) {
        const int m0 = jt * 16 + quad * 4;
        union { u16 q[4]; uint2 u; } pk;
        #pragma unroll
        for (int r = 0; r < 4; r++) pk.q[r] = f2b(acco[jt][r] * inv);
        *(uint2*)&out[orow + m0] = pk.u;
    }
}

// ---------------------------------------------------------------------------
// LayerNorm (single input stream; residual pre-added in GEMM epilogue).
// ---------------------------------------------------------------------------
__global__ __launch_bounds__(256) void ln_kernel(
    const u16* __restrict__ s_in,
    const float* __restrict__ g, const float* __restrict__ be, u16* __restrict__ out)
{
    int row = blockIdx.x * 4 + (threadIdx.x >> 6);
    int lane = threadIdx.x & 63;
    size_t base = (size_t)row * 512 + lane * 8;
    uint4 hv = *(const uint4*)&s_in[base];
    const u16* hp = (const u16*)&hv;
    float x[8]; float s = 0.f;
    #pragma unroll
    for (int i = 0; i < 8; i++) { x[i] = b2f(hp[i]); s += x[i]; }
    #pragma unroll
    for (int off = 32; off > 0; off >>= 1) s += __shfl_xor(s, off, 64);
    float m = s * (1.f / 512.f);
    float vs = 0.f;
    #pragma unroll
    for (int i = 0; i < 8; i++) { float t = x[i] - m; vs += t * t; }
    #pragma unroll
    for (int off = 32; off > 0; off >>= 1) vs += __shfl_xor(vs, off, 64);
    float rstd = rsqrtf(vs * (1.f / 512.f) + 1e-5f);
    union { u16 u[8]; uint4 v; } o;
    #pragma unroll
    for (int i = 0; i < 8; i++)
        o.u[i] = f2b((x[i] - m) * rstd * g[lane * 8 + i] + be[lane * 8 + i]);
    *(uint4*)&out[base] = o.v;
}

// ---------------------------------------------------------------------------
extern "C" void kernel_launch(void* const* d_in, const int* in_sizes, int n_in,
                              void* d_out, int out_size, void* d_ws, size_t ws_size,
                              hipStream_t stream)
{
    const int*   x  = (const int*)d_in[0];
    const float* E  = (const float*)d_in[1];
    const float* Wq = (const float*)d_in[2];
    const float* bq = (const float*)d_in[3];
    const float* Wk = (const float*)d_in[4];
    const float* bk = (const float*)d_in[5];
    const float* Wv = (const float*)d_in[6];
    const float* bv = (const float*)d_in[7];
    const float* Wo = (const float*)d_in[8];
    const float* bo = (const float*)d_in[9];
    const float* g1 = (const float*)d_in[10];
    const float* be1= (const float*)d_in[11];
    const float* W1 = (const float*)d_in[12];
    const float* b1 = (const float*)d_in[13];
    const float* W2 = (const float*)d_in[14];
    const float* b2 = (const float*)d_in[15];
    const float* g2 = (const float*)d_in[16];
    const float* be2= (const float*)d_in[17];
    const float* Wp = (const float*)d_in[18];
    const float* bp = (const float*)d_in[19];

    // --- fixed region: bf16 transposed weights + PE table + fp32 qkv bias ---
    char* p = (char*)d_ws;
    u16* qkvT = (u16*)p; p += (size_t)2 * 1536 * 512 * 2;
    u16* woT  = (u16*)p; p += (size_t)2 * 512 * 512 * 2;
    u16* w1T  = (u16*)p; p += (size_t)2 * 2048 * 512 * 2;
    u16* w2T  = (u16*)p; p += (size_t)2 * 512 * 2048 * 2;
    u16* wpT  = (u16*)p; p += (size_t)64 * 512 * 2;
    u16* pe   = (u16*)p; p += (size_t)T_SEQ * 256 * 2;     // 1 MiB
    float* bqkv = (float*)p; p += (size_t)16384;
    size_t fixed = (size_t)(p - (char*)d_ws);

    // --- adaptive batch group: Bg * 12.65 MiB ---
    const size_t perB = 12648448ULL;
    int Bg = 32;
    while (Bg > 1 && fixed + (size_t)Bg * perB > ws_size) Bg >>= 1;
    const int rows = Bg * T_SEQ;
    const int BHg = Bg * NHEADS;
    const int nbm = rows / 128;

    u16* h      = (u16*)p; p += (size_t)rows * 512 * 2;
    u16* qkvBig = (u16*)p; p += (size_t)rows * 2048 * 2;
    u16* am     = (u16*)p; p += (size_t)rows * 512 * 2;
    float* Z    = (float*)p; p += (size_t)BHg * NCHUNK * 64 * 4;
    u16* qkv = qkvBig;                        // rows x 1536 during attention
    u16* Sb  = qkvBig + (size_t)rows * 1536;  // bf16 S' tail
    u16* ff1 = qkvBig;                        // rows x 2048 during FF
    u16* o_  = qkvBig;                        // rows x 512 Wo output (h+attn)

    dim3 blk(256);

    // one-shot preprocessing (was 15 dispatches)
    prep_kernel<<<8236, blk, 0, stream>>>(
        Wq, Wk, Wv, Wo, W1, W2, Wp, bq, bk, bv,
        qkvT, woT, w1T, w2T, wpT, pe, bqkv);

    for (int b0 = 0; b0 < BATCH; b0 += Bg) {
        embed_kernel<<<rows * 2, blk, 0, stream>>>(x, E, pe, h, b0);

        for (int l = 0; l < 2; l++) {
            gemm_mx<2, false><<<dim3(nbm * 12), blk, 0, stream>>>(
                h, qkvT + (size_t)l * 786432, bqkv + l * 1536, nullptr, qkv,
                rows, 1536, 512, 1024, 12, 8);
            attn_chunk_sums<<<NCHUNK * BHg, blk, 0, stream>>>(qkv, Sb, Z, BHg);
            attn_prefix<<<BHg * 16, blk, 0, stream>>>(Sb, Z, BHg);
            attn_intra<<<NCHUNK * BHg, blk, 0, stream>>>(qkv, Sb, Z, am, BHg);
            gemm_mx<0, true><<<dim3(nbm * 4), blk, 0, stream>>>(
                am, woT + (size_t)l * 262144, bo + l * 512, h, o_,
                rows, 512, 512, 0, 4, 8);
            ln_kernel<<<rows / 4, blk, 0, stream>>>(o_, g1 + l * 512, be1 + l * 512, h);
            gemm_mx<1, false><<<dim3(nbm * 16), blk, 0, stream>>>(
                h, w1T + (size_t)l * 1048576, b1 + l * 2048, nullptr, ff1,
                rows, 2048, 512, 0, 16, 8);
            gemm_mx<0, true><<<dim3(nbm * 4), blk, 0, stream>>>(
                ff1, w2T + (size_t)l * 1048576, b2 + l * 512, h, am,
                rows, 512, 2048, 0, 4, 8);
            ln_kernel<<<rows / 4, blk, 0, stream>>>(am, g2 + l * 512, be2 + l * 512, h);
        }

        gemm_sm<64, 64, 2, 2><<<dim3(1, rows / 64), blk, 0, stream>>>(
            h, wpT, bp, (float*)d_out + (size_t)b0 * T_SEQ * 64, rows, 64, 512);
    }

    (void)in_sizes; (void)n_in; (void)out_size; (void)ws_size;
}

// Round 12
// 1521.776 us; speedup vs baseline: 1.2053x; 1.0260x over previous
//
#include <hip/hip_runtime.h>

// ---------------------------------------------------------------------------
// SequencePredictorRecurrentTransformer on MI355X (gfx950)
//
// I/O: fp32 (x int32). Internal: bf16 storage, fp32 accumulation.
// Layout [b][t][d] bt-major. Batch groups of Bg sized to ws_size.
//
// Round-12: gemm_mx switched to mfma_f32_32x32x16_bf16 (2x2 frags of 32x32
// per 64x64 wave tile, 4 K=16 steps per BK=64). Halves MFMA inst count,
// +17% FLOP/cyc (m119), fewer operand VGPRs. Layouts: C/D per m74/m101
// (col=lane&31, row=(reg&3)+8*(reg>>2)+4*(lane>>5)); A/B use the verified
// gfx950 K-doubling pattern (8 contiguous k per lane, m=lane&31,
// k=(lane>>5)*8+j). Everything else identical to round 11 (1561us).
// ---------------------------------------------------------------------------

typedef unsigned short u16;
typedef __bf16 bf16x8 __attribute__((ext_vector_type(8)));
typedef float f32x4 __attribute__((ext_vector_type(4)));
typedef float f32x16 __attribute__((ext_vector_type(16)));

#define T_SEQ 2048
#define BATCH 32
#define NHEADS 8
#define CT 64
#define NCHUNK 32             // T/CT

// skewed column offset for transposed LDS arrays (row r, t-index k)
#define SKEW(r, k) ((((k) + (((r) >> 3) << 3))) & 63)

__device__ __forceinline__ float b2f(u16 u) {
    union { unsigned int i; float f; } v; v.i = ((unsigned int)u) << 16; return v.f;
}
__device__ __forceinline__ u16 f2b(float f) {
    union { __bf16 b; u16 u; } v; v.b = (__bf16)f; return v.u;   // HW cvt, RNE
}

__device__ __forceinline__ void gl_lds16(const u16* g, u16* l) {
    __builtin_amdgcn_global_load_lds(
        (const __attribute__((address_space(1))) void*)g,
        (__attribute__((address_space(3))) void*)l,
        16, 0, 0);
}

// ---------------------------------------------------------------------------
// m97-structure GEMM, 32x32x16 MFMA: C[M,N] = act(A@BT^T + bias [+ R])
// BM=BN=128, BK=64, 4 waves x (64x64 = 2x2 frags of 32x32).
// XOR-swizzled global_load_lds staging (identical to round 11).
// ACT: 0=none, 1=relu, 2=phi(elu+1) where col < act_split.
// ---------------------------------------------------------------------------
template<int ACT, bool RES>
__global__ __launch_bounds__(256) void gemm_mx(
    const u16* __restrict__ A, const u16* __restrict__ BT,
    const float* __restrict__ bias, const u16* __restrict__ R,
    u16* __restrict__ C,
    int M, int N, int K, int act_split, int nbn, int GM)
{
    __shared__ __align__(16) u16 As[128 * 64];
    __shared__ __align__(16) u16 Bs[128 * 64];

    const int bid = blockIdx.x;
    const int gsz = GM * nbn;
    const int grp = bid / gsz, rm = bid % gsz;
    const int bm = (grp * GM + rm % GM) * 128;
    const int bn = (rm / GM) * 128;

    const int tid = threadIdx.x;
    const int lane = tid & 63;
    const int w = tid >> 6;
    const int l32 = lane & 31;         // 32x32 frag: m/n index
    const int kh  = lane >> 5;         // 0/1: k-half selector (8 elems each)
    const int wrow = (w >> 1) * 64, wcol = (w & 1) * 64;
    const int sr = lane >> 3;          // staging: row within 8-row chunk
    const int sg = lane & 7;           // staging: granule slot in row

    f32x16 acc[2][2] = {};

    for (int k0 = 0; k0 < K; k0 += 64) {
        #pragma unroll
        for (int ch4 = 0; ch4 < 4; ch4++) {
            const int chunk = w * 4 + ch4;        // 0..15 (8 rows each)
            const int r = chunk * 8 + sr;         // 0..127
            const int gs = sg ^ (r & 7);          // swizzled source granule
            gl_lds16(A  + (size_t)(bm + r) * K + k0 + gs * 8, As + chunk * 512);
            gl_lds16(BT + (size_t)(bn + r) * K + k0 + gs * 8, Bs + chunk * 512);
        }
        __syncthreads();
        #pragma unroll
        for (int step = 0; step < 4; step++) {    // K=16 per step
            const int gA = step * 2 + kh;          // granule of this lane's 8 k
            bf16x8 af[2], bfv[2];
            #pragma unroll
            for (int i = 0; i < 2; i++) {
                const int r = wrow + i * 32 + l32;
                const int gq = gA ^ (r & 7);
                af[i] = *(const bf16x8*)&As[r * 64 + gq * 8];
            }
            #pragma unroll
            for (int j = 0; j < 2; j++) {
                const int r = wcol + j * 32 + l32;
                const int gq = gA ^ (r & 7);
                bfv[j] = *(const bf16x8*)&Bs[r * 64 + gq * 8];
            }
            #pragma unroll
            for (int i = 0; i < 2; i++)
                #pragma unroll
                for (int j = 0; j < 2; j++)
                    acc[i][j] = __builtin_amdgcn_mfma_f32_32x32x16_bf16(
                        af[i], bfv[j], acc[i][j], 0, 0, 0);
        }
        __syncthreads();
    }

    // Epilogue. D (m74/m101): col = lane&31, row = (reg&3)+8*(reg>>2)+4*kh.
    #pragma unroll
    for (int i = 0; i < 2; i++) {
        const int row0 = bm + wrow + i * 32 + 4 * kh;
        #pragma unroll
        for (int j = 0; j < 2; j++) {
            const int col = bn + wcol + j * 32 + l32;
            const float bb = bias[col];
            const bool phi = (ACT == 2) && (col < act_split);
            #pragma unroll
            for (int reg = 0; reg < 16; reg++) {
                const int m = row0 + (reg & 3) + 8 * (reg >> 2);
                float v = acc[i][j][reg] + bb;
                if (RES) v += b2f(R[(size_t)m * N + col]);
                if (ACT == 1) v = fmaxf(v, 0.f);
                if (ACT == 2) { if (phi) v = (v > 0.f) ? (v + 1.f) : __expf(v); }
                C[(size_t)m * N + col] = f2b(v);
            }
        }
    }
}

// ---------------------------------------------------------------------------
// Small-N GEMM (final projection, N=64): fp32 out, swapped epilogue (16B st).
// ---------------------------------------------------------------------------
template<int BM, int BN, int WM, int WN>
__global__ __launch_bounds__(WM*WN*64) void gemm_sm(
    const u16* __restrict__ A, const u16* __restrict__ BT,
    const float* __restrict__ bias, float* __restrict__ C,
    int M, int N, int K)
{
    constexpr int BK = 32;
    constexpr int LDT = BK + 8;
    constexpr int NTHR = WM * WN * 64;
    __shared__ __align__(16) u16 As[BM * LDT];
    __shared__ __align__(16) u16 Bs[BN * LDT];

    const int tid = threadIdx.x;
    const int bm = blockIdx.y * BM;
    const int bn = blockIdx.x * BN;
    const int lane = tid & 63;
    const int wid = tid >> 6;
    const int wrow = (wid / WN) * (BM / WM);
    const int wcol = (wid % WN) * (BN / WN);
    constexpr int FM = BM / WM / 16;
    constexpr int FN = BN / WN / 16;
    const int lrow = lane & 15;
    const int lk = (lane >> 4) * 8;

    f32x4 acc[FM][FN] = {};

    for (int k0 = 0; k0 < K; k0 += BK) {
        #pragma unroll
        for (int g0 = 0; g0 < BM * 4; g0 += NTHR) {
            int g = g0 + tid;
            int row = g >> 2, kk = (g & 3) * 8;
            *(uint4*)&As[row * LDT + kk] =
                *(const uint4*)&A[(size_t)(bm + row) * K + k0 + kk];
        }
        #pragma unroll
        for (int g0 = 0; g0 < BN * 4; g0 += NTHR) {
            int g = g0 + tid;
            int row = g >> 2, kk = (g & 3) * 8;
            *(uint4*)&Bs[row * LDT + kk] =
                *(const uint4*)&BT[(size_t)(bn + row) * K + k0 + kk];
        }
        __syncthreads();
        bf16x8 af[FM], bfv[FN];
        #pragma unroll
        for (int i = 0; i < FM; i++)
            af[i] = *(const bf16x8*)&As[(wrow + i * 16 + lrow) * LDT + lk];
        #pragma unroll
        for (int j = 0; j < FN; j++)
            bfv[j] = *(const bf16x8*)&Bs[(wcol + j * 16 + lrow) * LDT + lk];
        #pragma unroll
        for (int i = 0; i < FM; i++)
            #pragma unroll
            for (int j = 0; j < FN; j++)
                acc[i][j] = __builtin_amdgcn_mfma_f32_16x16x32_bf16(
                    bfv[j], af[i], acc[i][j], 0, 0, 0);   // swapped
        __syncthreads();
    }

    #pragma unroll
    for (int i = 0; i < FM; i++) {
        const int row = bm + wrow + i * 16 + lrow;
        #pragma unroll
        for (int j = 0; j < FN; j++) {
            const int col0 = bn + wcol + j * 16 + (lane >> 4) * 4;
            const float4 bb = *(const float4*)&bias[col0];
            float4 o = { acc[i][j][0] + bb.x, acc[i][j][1] + bb.y,
                         acc[i][j][2] + bb.z, acc[i][j][3] + bb.w };
            *(float4*)&C[(size_t)row * N + col0] = o;
        }
    }
}

// ---------------------------------------------------------------------------
// Mega-preprocess: ALL weight transposes (fp32->bf16) + PE table + qkv bias
// concat in ONE dispatch. Block ranges (block-uniform branches).
// ---------------------------------------------------------------------------
__global__ __launch_bounds__(256) void prep_kernel(
    const float* __restrict__ Wq, const float* __restrict__ Wk,
    const float* __restrict__ Wv, const float* __restrict__ Wo,
    const float* __restrict__ W1, const float* __restrict__ W2,
    const float* __restrict__ Wp,
    const float* __restrict__ bq, const float* __restrict__ bk,
    const float* __restrict__ bv,
    u16* __restrict__ qkvT, u16* __restrict__ woT, u16* __restrict__ w1T,
    u16* __restrict__ w2T, u16* __restrict__ wpT, u16* __restrict__ pe,
    float* __restrict__ bqkv)
{
    __shared__ float tile[32][33];
    const int bid = blockIdx.x;
    const float* src; u16* dst; int K, N, bx, by;

    if (bid < 1536) {
        int l = bid / 768, r = bid % 768, m = r >> 8, t = r & 255;
        const float* s3[3] = { Wq, Wk, Wv };            // m block-uniform
        src = s3[m] + (size_t)l * 262144;
        dst = qkvT + (size_t)l * 786432 + (size_t)m * 262144;
        K = 512; N = 512; bx = t & 15; by = t >> 4;
    } else if (bid < 2048) {
        int r = bid - 1536, l = r >> 8, t = r & 255;
        src = Wo + (size_t)l * 262144; dst = woT + (size_t)l * 262144;
        K = 512; N = 512; bx = t & 15; by = t >> 4;
    } else if (bid < 4096) {
        int r = bid - 2048, l = r >> 10, t = r & 1023;
        src = W1 + (size_t)l * 1048576; dst = w1T + (size_t)l * 1048576;
        K = 512; N = 2048; bx = t & 63; by = t >> 6;
    } else if (bid < 6144) {
        int r = bid - 4096, l = r >> 10, t = r & 1023;
        src = W2 + (size_t)l * 1048576; dst = w2T + (size_t)l * 1048576;
        K = 2048; N = 512; bx = t & 15; by = t >> 4;
    } else if (bid < 6176) {
        int t = bid - 6144;
        src = Wp; dst = wpT; K = 512; N = 64; bx = t & 1; by = t >> 1;
    } else if (bid < 8224) {
        int id = (bid - 6176) * 256 + threadIdx.x;      // < 2048*256
        int t = id >> 8, j = id & 255;
        int i = j >> 1;
        float div = expf(-(float)(2 * i) * (9.210340371976184f / 256.f));
        float arg = (float)t * div;
        pe[id] = f2b((j & 1) ? cosf(arg) : sinf(arg));
        return;
    } else {
        int id = (bid - 8224) * 256 + threadIdx.x;
        if (id < 3072) {
            int l = id / 1536, i2 = id % 1536;
            float v = (i2 < 512) ? bq[l * 512 + i2]
                    : (i2 < 1024) ? bk[l * 512 + i2 - 512]
                                  : bv[l * 512 + i2 - 1024];
            bqkv[id] = v;
        }
        return;
    }

    // 32x32 transpose tile: dst[N][K] = bf16(src[K][N])
    int tx = threadIdx.x & 31, ty = threadIdx.x >> 5;
    #pragma unroll
    for (int yy = 0; yy < 4; yy++) {
        int k = by * 32 + ty + yy * 8;
        tile[ty + yy * 8][tx] = src[(size_t)k * N + bx * 32 + tx];
    }
    __syncthreads();
    #pragma unroll
    for (int yy = 0; yy < 4; yy++) {
        int n = bx * 32 + ty + yy * 8;
        dst[(size_t)n * K + by * 32 + tx] = f2b(tile[tx][ty + yy * 8]);
    }
}

// ---------------------------------------------------------------------------
// Embedding (bt-major): pure gather from E and the PE table.
// ---------------------------------------------------------------------------
__global__ __launch_bounds__(256) void embed_kernel(
    const int* __restrict__ x, const float* __restrict__ E,
    const u16* __restrict__ pe, u16* __restrict__ h, int b0)
{
    int e = blockIdx.x * 256 + threadIdx.x;
    int r = e >> 9;
    int c = e & 511;
    int t = r & (T_SEQ - 1);
    int b = b0 + (r >> 11);
    u16 o;
    if (c < 256) o = f2b(E[x[t * BATCH + b] * 256 + c]);
    else         o = pe[t * 256 + (c - 256)];
    h[e] = o;
}

// ---------------------------------------------------------------------------
// Phase A (MFMA): S'_c[m][d] = sum_t V[t][m]*K[t][d] -> bf16; Z_c[d]=sum K.
// Loader: uint4 global; skewed transposed LDS stores (static reg indexing).
// ---------------------------------------------------------------------------
__global__ __launch_bounds__(256) void attn_chunk_sums(
    const u16* __restrict__ qkv, u16* __restrict__ S, float* __restrict__ Z,
    int BHg)
{
    __shared__ __align__(16) u16 Kt[64 * 72], Vt[64 * 72];   // skewed [d][t]
    int bid = blockIdx.x;
    int bh = bid % BHg, c = bid / BHg;
    int bl = bh >> 3, hh = bh & 7;
    {
        const int m  = threadIdx.x & 7;
        const int d0 = m * 8;
        #pragma unroll
        for (int p = 0; p < 2; p++) {
            const int t = p * 32 + (threadIdx.x >> 3);
            size_t rr = ((size_t)(bl * T_SEQ + c * 64 + t)) * 1536 + hh * 64 + d0;
            uint4 kv = *(const uint4*)&qkv[rr + 512];
            uint4 vv = *(const uint4*)&qkv[rr + 1024];
            const u16* kp = (const u16*)&kv;
            const u16* vp = (const u16*)&vv;
            const int sk = (t + d0) & 63;         // skew col for rows d0..d0+7
            u16* kb = &Kt[d0 * 72 + sk];
            u16* vb = &Vt[d0 * 72 + sk];
            #pragma unroll
            for (int s = 0; s < 8; s++) { kb[s * 72] = kp[s]; vb[s * 72] = vp[s]; }
        }
    }
    __syncthreads();
    int lane = threadIdx.x & 63;
    int w = threadIdx.x >> 6;
    int lrow = lane & 15, quad = lane >> 4;
    int m0 = w * 16;
    f32x4 acc[4] = {};
    #pragma unroll
    for (int k0 = 0; k0 < 64; k0 += 32) {
        const int ra = m0 + lrow;
        bf16x8 af = *(const bf16x8*)&Vt[ra * 72 + SKEW(ra, k0 + quad * 8)];
        #pragma unroll
        for (int jt = 0; jt < 4; jt++) {
            const int rb = jt * 16 + lrow;
            bf16x8 bf = *(const bf16x8*)&Kt[rb * 72 + SKEW(rb, k0 + quad * 8)];
            acc[jt] = __builtin_amdgcn_mfma_f32_16x16x32_bf16(bf, af, acc[jt], 0, 0, 0);
        }
    }
    size_t base = ((size_t)c * BHg + bh) * 4096;
    const int m = m0 + lrow;
    #pragma unroll
    for (int jt = 0; jt < 4; jt++) {
        const int d0 = jt * 16 + quad * 4;
        union { u16 q[4]; uint2 u; } pk;
        #pragma unroll
        for (int r = 0; r < 4; r++) pk.q[r] = f2b(acc[jt][r]);
        *(uint2*)&S[base + m * 64 + d0] = pk.u;
    }
    if (threadIdx.x < 64) {
        const int d = threadIdx.x;
        float z = 0.f;
        #pragma unroll
        for (int t8 = 0; t8 < 64; t8 += 8) {
            bf16x8 kk = *(const bf16x8*)&Kt[d * 72 + SKEW(d, t8)];
            #pragma unroll
            for (int u = 0; u < 8; u++) z += (float)kk[u];
        }
        Z[((size_t)c * BHg + bh) * 64 + d] = z;
    }
}

// ---------------------------------------------------------------------------
// Phase B: exclusive prefix over chunks; register scan, loads all in flight.
// ---------------------------------------------------------------------------
__global__ __launch_bounds__(256) void attn_prefix(
    u16* __restrict__ S, float* __restrict__ Z, int BHg)
{
    int gid = blockIdx.x * 256 + threadIdx.x;   // < BHg*4096
    int bh = gid >> 12, e = gid & 4095;
    size_t stride = (size_t)BHg * 4096;
    size_t base = (size_t)bh * 4096 + e;
    float v[NCHUNK];
    #pragma unroll
    for (int c = 0; c < NCHUNK; c++) v[c] = b2f(S[base + c * stride]);
    float run = 0.f;
    #pragma unroll
    for (int c = 0; c < NCHUNK; c++) {
        float t = v[c]; S[base + c * stride] = f2b(run); run += t;
    }
    if (gid < BHg * 64) {
        size_t zb = (size_t)gid;
        size_t zs = (size_t)BHg * 64;
        float zv[NCHUNK];
        #pragma unroll
        for (int c = 0; c < NCHUNK; c++) zv[c] = Z[zb + c * zs];
        float zr = 0.f;
        #pragma unroll
        for (int c = 0; c < NCHUNK; c++) {
            float t = zv[c]; Z[zb + c * zs] = zr; zr += t;
        }
    }
}

// ---------------------------------------------------------------------------
// Phase C (MFMA): P=QK^T masked; O=(P@V + Q@S')/den.
// Loader: uint4 global + uint4 row-major LDS; skewed Vt. Ps aliases Ks.
// ---------------------------------------------------------------------------
__global__ __launch_bounds__(256) void attn_intra(
    const u16* __restrict__ qkv, const u16* __restrict__ Sp,
    const float* __restrict__ Zp, u16* __restrict__ out, int BHg)
{
    __shared__ __align__(16) u16 Qs[64 * 72], Ks[64 * 72], Vt[64 * 72],
                                 Ssh[64 * 72];
    __shared__ float Zsh[64], den2sh[64], den1sh[64];
    u16* Ps = Ks;                              // Ks dead after P-mfma
    int bid = blockIdx.x;
    int bh = bid % BHg, c = bid / BHg;
    int bl = bh >> 3, hh = bh & 7;
    size_t sbase = ((size_t)c * BHg + bh) * 4096;
    {
        const int m  = threadIdx.x & 7;
        const int d0 = m * 8;
        #pragma unroll
        for (int p = 0; p < 2; p++) {
            const int t = p * 32 + (threadIdx.x >> 3);
            size_t rr = ((size_t)(bl * T_SEQ + c * 64 + t)) * 1536 + hh * 64 + d0;
            *(uint4*)&Qs[t * 72 + d0]  = *(const uint4*)&qkv[rr];
            *(uint4*)&Ks[t * 72 + d0]  = *(const uint4*)&qkv[rr + 512];
            *(uint4*)&Ssh[t * 72 + d0] = *(const uint4*)&Sp[sbase + t * 64 + d0];
            uint4 vv = *(const uint4*)&qkv[rr + 1024];
            const u16* vp = (const u16*)&vv;
            const int sk = (t + d0) & 63;
            u16* vb = &Vt[d0 * 72 + sk];
            #pragma unroll
            for (int s = 0; s < 8; s++) vb[s * 72] = vp[s];
        }
    }
    if (threadIdx.x < 64)
        Zsh[threadIdx.x] = Zp[((size_t)c * BHg + bh) * 64 + threadIdx.x];
    __syncthreads();

    if (threadIdx.x < 64) {
        float s = 0.f;
        #pragma unroll
        for (int d8 = 0; d8 < 64; d8 += 8) {
            bf16x8 qq = *(const bf16x8*)&Qs[threadIdx.x * 72 + d8];
            #pragma unroll
            for (int u = 0; u < 8; u++) s += (float)qq[u] * Zsh[d8 + u];
        }
        den2sh[threadIdx.x] = s;
    }

    int lane = threadIdx.x & 63;
    int w = threadIdx.x >> 6;
    int lrow = lane & 15, quad = lane >> 4;
    int i0 = w * 16;

    // P = Q @ K^T (row = i via reg)
    f32x4 accp[4] = {};
    #pragma unroll
    for (int k0 = 0; k0 < 64; k0 += 32) {
        bf16x8 af = *(const bf16x8*)&Qs[(i0 + lrow) * 72 + k0 + quad * 8];
        #pragma unroll
        for (int jt = 0; jt < 4; jt++) {
            bf16x8 bf = *(const bf16x8*)&Ks[(jt * 16 + lrow) * 72 + k0 + quad * 8];
            accp[jt] = __builtin_amdgcn_mfma_f32_16x16x32_bf16(af, bf, accp[jt], 0, 0, 0);
        }
    }
    __syncthreads();                           // all Ks reads done before Ps writes
    #pragma unroll
    for (int r = 0; r < 4; r++) {
        int row = i0 + quad * 4 + r;
        float d1 = 0.f;
        #pragma unroll
        for (int jt = 0; jt < 4; jt++) {
            int col = jt * 16 + lrow;
            float pv = (col <= row) ? accp[jt][r] : 0.f;
            d1 += pv;
            Ps[row * 72 + col] = f2b(pv);
        }
        #pragma unroll
        for (int off = 1; off < 16; off <<= 1)
            d1 += __shfl_xor(d1, off, 64);
        if (lrow == 0) den1sh[row] = d1;
    }
    __syncthreads();

    // O = Ps @ V + Q @ S'  (swapped: first operand = m side)
    f32x4 acco[4] = {};
    #pragma unroll
    for (int k0 = 0; k0 < 64; k0 += 32) {
        bf16x8 ps = *(const bf16x8*)&Ps[(i0 + lrow) * 72 + k0 + quad * 8];
        #pragma unroll
        for (int jt = 0; jt < 4; jt++) {
            const int rv = jt * 16 + lrow;
            bf16x8 vf = *(const bf16x8*)&Vt[rv * 72 + SKEW(rv, k0 + quad * 8)];
            acco[jt] = __builtin_amdgcn_mfma_f32_16x16x32_bf16(vf, ps, acco[jt], 0, 0, 0);
        }
    }
    #pragma unroll
    for (int k0 = 0; k0 < 64; k0 += 32) {
        bf16x8 qf = *(const bf16x8*)&Qs[(i0 + lrow) * 72 + k0 + quad * 8];
        #pragma unroll
        for (int jt = 0; jt < 4; jt++) {
            bf16x8 sf = *(const bf16x8*)&Ssh[(jt * 16 + lrow) * 72 + k0 + quad * 8];
            acco[jt] = __builtin_amdgcn_mfma_f32_16x16x32_bf16(sf, qf, acco[jt], 0, 0, 0);
        }
    }
    const int i = i0 + lrow;
    const float inv = 1.f / (den1sh[i] + den2sh[i] + 1e-6f);
    size_t orow = ((size_t)(bl * T_SEQ + c * 64 + i)) * 512 + hh * 64;
    #pragma unroll
    for (int jt = 0; jt < 4; jt++) {
        const int m0 = jt * 16 + quad * 4;
        union { u16 q[4]; uint2 u; } pk;
        #pragma unroll
        for (int r = 0; r < 4; r++) pk.q[r] = f2b(acco[jt][r] * inv);
        *(uint2*)&out[orow + m0] = pk.u;
    }
}

// ---------------------------------------------------------------------------
// LayerNorm (single input stream; residual pre-added in GEMM epilogue).
// ---------------------------------------------------------------------------
__global__ __launch_bounds__(256) void ln_kernel(
    const u16* __restrict__ s_in,
    const float* __restrict__ g, const float* __restrict__ be, u16* __restrict__ out)
{
    int row = blockIdx.x * 4 + (threadIdx.x >> 6);
    int lane = threadIdx.x & 63;
    size_t base = (size_t)row * 512 + lane * 8;
    uint4 hv = *(const uint4*)&s_in[base];
    const u16* hp = (const u16*)&hv;
    float x[8]; float s = 0.f;
    #pragma unroll
    for (int i = 0; i < 8; i++) { x[i] = b2f(hp[i]); s += x[i]; }
    #pragma unroll
    for (int off = 32; off > 0; off >>= 1) s += __shfl_xor(s, off, 64);
    float m = s * (1.f / 512.f);
    float vs = 0.f;
    #pragma unroll
    for (int i = 0; i < 8; i++) { float t = x[i] - m; vs += t * t; }
    #pragma unroll
    for (int off = 32; off > 0; off >>= 1) vs += __shfl_xor(vs, off, 64);
    float rstd = rsqrtf(vs * (1.f / 512.f) + 1e-5f);
    union { u16 u[8]; uint4 v; } o;
    #pragma unroll
    for (int i = 0; i < 8; i++)
        o.u[i] = f2b((x[i] - m) * rstd * g[lane * 8 + i] + be[lane * 8 + i]);
    *(uint4*)&out[base] = o.v;
}

// ---------------------------------------------------------------------------
extern "C" void kernel_launch(void* const* d_in, const int* in_sizes, int n_in,
                              void* d_out, int out_size, void* d_ws, size_t ws_size,
                              hipStream_t stream)
{
    const int*   x  = (const int*)d_in[0];
    const float* E  = (const float*)d_in[1];
    const float* Wq = (const float*)d_in[2];
    const float* bq = (const float*)d_in[3];
    const float* Wk = (const float*)d_in[4];
    const float* bk = (const float*)d_in[5];
    const float* Wv = (const float*)d_in[6];
    const float* bv = (const float*)d_in[7];
    const float* Wo = (const float*)d_in[8];
    const float* bo = (const float*)d_in[9];
    const float* g1 = (const float*)d_in[10];
    const float* be1= (const float*)d_in[11];
    const float* W1 = (const float*)d_in[12];
    const float* b1 = (const float*)d_in[13];
    const float* W2 = (const float*)d_in[14];
    const float* b2 = (const float*)d_in[15];
    const float* g2 = (const float*)d_in[16];
    const float* be2= (const float*)d_in[17];
    const float* Wp = (const float*)d_in[18];
    const float* bp = (const float*)d_in[19];

    // --- fixed region: bf16 transposed weights + PE table + fp32 qkv bias ---
    char* p = (char*)d_ws;
    u16* qkvT = (u16*)p; p += (size_t)2 * 1536 * 512 * 2;
    u16* woT  = (u16*)p; p += (size_t)2 * 512 * 512 * 2;
    u16* w1T  = (u16*)p; p += (size_t)2 * 2048 * 512 * 2;
    u16* w2T  = (u16*)p; p += (size_t)2 * 512 * 2048 * 2;
    u16* wpT  = (u16*)p; p += (size_t)64 * 512 * 2;
    u16* pe   = (u16*)p; p += (size_t)T_SEQ * 256 * 2;     // 1 MiB
    float* bqkv = (float*)p; p += (size_t)16384;
    size_t fixed = (size_t)(p - (char*)d_ws);

    // --- adaptive batch group: Bg * 12.65 MiB ---
    const size_t perB = 12648448ULL;
    int Bg = 32;
    while (Bg > 1 && fixed + (size_t)Bg * perB > ws_size) Bg >>= 1;
    const int rows = Bg * T_SEQ;
    const int BHg = Bg * NHEADS;
    const int nbm = rows / 128;

    u16* h      = (u16*)p; p += (size_t)rows * 512 * 2;
    u16* qkvBig = (u16*)p; p += (size_t)rows * 2048 * 2;
    u16* am     = (u16*)p; p += (size_t)rows * 512 * 2;
    float* Z    = (float*)p; p += (size_t)BHg * NCHUNK * 64 * 4;
    u16* qkv = qkvBig;                        // rows x 1536 during attention
    u16* Sb  = qkvBig + (size_t)rows * 1536;  // bf16 S' tail
    u16* ff1 = qkvBig;                        // rows x 2048 during FF
    u16* o_  = qkvBig;                        // rows x 512 Wo output (h+attn)

    dim3 blk(256);

    // one-shot preprocessing
    prep_kernel<<<8236, blk, 0, stream>>>(
        Wq, Wk, Wv, Wo, W1, W2, Wp, bq, bk, bv,
        qkvT, woT, w1T, w2T, wpT, pe, bqkv);

    for (int b0 = 0; b0 < BATCH; b0 += Bg) {
        embed_kernel<<<rows * 2, blk, 0, stream>>>(x, E, pe, h, b0);

        for (int l = 0; l < 2; l++) {
            gemm_mx<2, false><<<dim3(nbm * 12), blk, 0, stream>>>(
                h, qkvT + (size_t)l * 786432, bqkv + l * 1536, nullptr, qkv,
                rows, 1536, 512, 1024, 12, 8);
            attn_chunk_sums<<<NCHUNK * BHg, blk, 0, stream>>>(qkv, Sb, Z, BHg);
            attn_prefix<<<BHg * 16, blk, 0, stream>>>(Sb, Z, BHg);
            attn_intra<<<NCHUNK * BHg, blk, 0, stream>>>(qkv, Sb, Z, am, BHg);
            gemm_mx<0, true><<<dim3(nbm * 4), blk, 0, stream>>>(
                am, woT + (size_t)l * 262144, bo + l * 512, h, o_,
                rows, 512, 512, 0, 4, 8);
            ln_kernel<<<rows / 4, blk, 0, stream>>>(o_, g1 + l * 512, be1 + l * 512, h);
            gemm_mx<1, false><<<dim3(nbm * 16), blk, 0, stream>>>(
                h, w1T + (size_t)l * 1048576, b1 + l * 2048, nullptr, ff1,
                rows, 2048, 512, 0, 16, 8);
            gemm_mx<0, true><<<dim3(nbm * 4), blk, 0, stream>>>(
                ff1, w2T + (size_t)l * 1048576, b2 + l * 512, h, am,
                rows, 512, 2048, 0, 4, 8);
            ln_kernel<<<rows / 4, blk, 0, stream>>>(am, g2 + l * 512, be2 + l * 512, h);
        }

        gemm_sm<64, 64, 2, 2><<<dim3(1, rows / 64), blk, 0, stream>>>(
            h, wpT, bp, (float*)d_out + (size_t)b0 * T_SEQ * 64, rows, 64, 512);
    }

    (void)in_sizes; (void)n_in; (void)out_size; (void)ws_size;
}